// Round 1
// baseline (1073.308 us; speedup 1.0000x reference)
//
#include <hip/hip_runtime.h>
#include <cstddef>

// Problem constants (from reference)
static constexpr int Nn    = 20000;
static constexpr int Ee    = 320000;
static constexpr int Vv    = 100;
static constexpr int Hh    = 128;
static constexpr int HEADS = 3;
static constexpr int Bb    = 200;
static constexpr float NEG = 0.2f;
static constexpr float EPS = 1e-5f;

// ---------------------------------------------------------------------------
// CSR build: histogram over dst, single-block scan, fill
// ---------------------------------------------------------------------------
__global__ void hist_dst(const int* __restrict__ dst, int* __restrict__ deg) {
    for (int i = blockIdx.x * blockDim.x + threadIdx.x; i < Ee; i += gridDim.x * blockDim.x)
        atomicAdd(&deg[dst[i]], 1);
}

__global__ __launch_bounds__(1024) void scan_offsets(const int* __restrict__ deg,
                                                     int* __restrict__ offs,
                                                     int* __restrict__ cur) {
    __shared__ int sums[1024];
    const int tid = threadIdx.x;
    const int per = (Nn + 1023) >> 10;          // 20
    int begin = tid * per;
    int end = begin + per; if (end > Nn) end = Nn;
    if (begin > Nn) begin = Nn;
    int s = 0;
    for (int i = begin; i < end; i++) s += deg[i];
    sums[tid] = s;
    __syncthreads();
    // Hillis-Steele inclusive scan
    for (int off = 1; off < 1024; off <<= 1) {
        int v = (tid >= off) ? sums[tid - off] : 0;
        __syncthreads();
        sums[tid] += v;
        __syncthreads();
    }
    int run = sums[tid] - s;                    // exclusive prefix
    for (int i = begin; i < end; i++) {
        offs[i] = run; cur[i] = run;
        run += deg[i];
    }
    if (end == Nn) offs[Nn] = run;              // == Ee (same value from all writers)
}

__global__ void fill_csr(const int* __restrict__ dst, int* __restrict__ cur,
                         int* __restrict__ eidx) {
    for (int i = blockIdx.x * blockDim.x + threadIdx.x; i < Ee; i += gridDim.x * blockDim.x) {
        int p = atomicAdd(&cur[dst[i]], 1);
        eidx[p] = i;
    }
}

// ---------------------------------------------------------------------------
// Generic fp32 GEMM: C[M,N] = A[M,K] @ B[K,N] (+ bias[N])
// BM=128, BN=64, BK=16, 256 threads, 8x4 micro-tile. K % 16 == 0, N % 64 == 0.
// ---------------------------------------------------------------------------
__global__ __launch_bounds__(256) void gemm_f32(const float* __restrict__ A,
                                                const float* __restrict__ Bm,
                                                const float* __restrict__ bias,
                                                float* __restrict__ C,
                                                int M, int N, int K) {
    __shared__ float As[16][132];   // [k][m], pad 132 -> 2-way max (free)
    __shared__ float Bs[16][64];    // [k][n]
    const int tid = threadIdx.x;
    const int tx = tid & 15;        // col group 0..15
    const int ty = tid >> 4;        // row group 0..15
    const int row0 = blockIdx.y * 128;
    const int col0 = blockIdx.x * 64;

    float c[8][4];
#pragma unroll
    for (int i = 0; i < 8; i++)
#pragma unroll
        for (int j = 0; j < 4; j++) c[i][j] = 0.f;

    for (int kb = 0; kb < K; kb += 16) {
        // A tile: 128 rows x 16 k = 512 float4, 2 per thread
#pragma unroll
        for (int l = 0; l < 2; l++) {
            int idx = tid + l * 256;        // 0..511
            int m = idx >> 2;               // 0..127
            int kq = (idx & 3) * 4;         // 0,4,8,12
            int gr = row0 + m;
            float4 v;
            if (gr < M) v = *(const float4*)(A + (size_t)gr * K + kb + kq);
            else        v = make_float4(0.f, 0.f, 0.f, 0.f);
            As[kq + 0][m] = v.x; As[kq + 1][m] = v.y;
            As[kq + 2][m] = v.z; As[kq + 3][m] = v.w;
        }
        // B tile: 16 k x 64 cols = 256 float4, 1 per thread
        {
            int k = tid >> 4;               // 0..15
            int nq = (tid & 15) * 4;        // 0..60
            float4 v = *(const float4*)(Bm + (size_t)(kb + k) * N + col0 + nq);
            *(float4*)(&Bs[k][nq]) = v;
        }
        __syncthreads();
#pragma unroll
        for (int k = 0; k < 16; k++) {
            float a[8], b[4];
#pragma unroll
            for (int i = 0; i < 8; i++) a[i] = As[k][ty * 8 + i];
#pragma unroll
            for (int j = 0; j < 4; j++) b[j] = Bs[k][tx * 4 + j];
#pragma unroll
            for (int i = 0; i < 8; i++)
#pragma unroll
                for (int j = 0; j < 4; j++) c[i][j] += a[i] * b[j];
        }
        __syncthreads();
    }
#pragma unroll
    for (int j = 0; j < 4; j++) {
        int col = col0 + tx * 4 + j;
        float bb = bias ? bias[col] : 0.f;
#pragma unroll
        for (int i = 0; i < 8; i++) {
            int row = row0 + ty * 8 + i;
            if (row < M) C[(size_t)row * N + col] = c[i][j] + bb;
        }
    }
}

// ---------------------------------------------------------------------------
// proj epilogue: hcur = gemm_out + projW[wid] + projB; readout0 accumulate
// ---------------------------------------------------------------------------
__global__ void proj_epilogue(const float* __restrict__ res, const float* __restrict__ projW,
                              const float* __restrict__ projB, const int* __restrict__ wid,
                              const int* __restrict__ gid, float* __restrict__ hcur,
                              float* __restrict__ reado, int* __restrict__ gcnt) {
    int n = blockIdx.x, tid = threadIdx.x;
    float v = res[(size_t)n * Hh + tid] + projW[(size_t)wid[n] * Hh + tid] + projB[tid];
    hcur[(size_t)n * Hh + tid] = v;
    atomicAdd(&reado[(size_t)gid[n] * Hh + tid], v);
    if (tid == 0) atomicAdd(&gcnt[gid[n]], 1);
}

// ---------------------------------------------------------------------------
// per-(node) attention dot: a_src[n,h] = <wv[n,h,:], att[h,:128]>, a_dst with att[h,128:]
// ---------------------------------------------------------------------------
__global__ void att_dots(const float* __restrict__ wv, const float* __restrict__ att,
                         float* __restrict__ asrc, float* __restrict__ adst) {
    int n = blockIdx.x, tid = threadIdx.x;
    __shared__ float red[2][128];
    for (int hd = 0; hd < HEADS; hd++) {
        float w = wv[(size_t)n * 384 + hd * 128 + tid];
        red[0][tid] = w * att[hd * 256 + tid];
        red[1][tid] = w * att[hd * 256 + 128 + tid];
        __syncthreads();
        for (int o = 64; o > 0; o >>= 1) {
            if (tid < o) { red[0][tid] += red[0][tid + o]; red[1][tid] += red[1][tid + o]; }
            __syncthreads();
        }
        if (tid == 0) { asrc[n * 3 + hd] = red[0][0]; adst[n * 3 + hd] = red[1][0]; }
        __syncthreads();
    }
}

// ---------------------------------------------------------------------------
// Per-dst-node softmax attention + aggregation (no atomics; CSR)
// agg[n,h,:] = sum_e softmax(attn)_e * wv[src_e,h,:]
// ---------------------------------------------------------------------------
__global__ __launch_bounds__(128) void gat_aggregate(const float* __restrict__ wv,
                                                     const float* __restrict__ asrc,
                                                     const float* __restrict__ adst,
                                                     const int* __restrict__ offs,
                                                     const int* __restrict__ eidx,
                                                     const int* __restrict__ srcv,
                                                     float* __restrict__ agg) {
    const int n = blockIdx.x, tid = threadIdx.x;
    const int start = offs[n], end = offs[n + 1];
    const int deg = end - start;
    if (deg == 0) {
        for (int j = tid; j < 384; j += 128) agg[(size_t)n * 384 + j] = 0.f;
        return;
    }
    __shared__ float red[128];
    __shared__ float s_sc[128];
    __shared__ int   s_src[128];
    for (int hd = 0; hd < HEADS; hd++) {
        const float adn = adst[n * 3 + hd];
        // pass 1: max
        float mx = -INFINITY;
        for (int i = tid; i < deg; i += 128) {
            int sn = srcv[eidx[start + i]];
            float a = asrc[sn * 3 + hd] + adn;
            a = a >= 0.f ? a : NEG * a;
            mx = fmaxf(mx, a);
        }
        red[tid] = mx; __syncthreads();
        for (int o = 64; o > 0; o >>= 1) { if (tid < o) red[tid] = fmaxf(red[tid], red[tid + o]); __syncthreads(); }
        const float m = red[0]; __syncthreads();
        // pass 2: sum of exp
        float sm = 0.f;
        for (int i = tid; i < deg; i += 128) {
            int sn = srcv[eidx[start + i]];
            float a = asrc[sn * 3 + hd] + adn;
            a = a >= 0.f ? a : NEG * a;
            sm += __expf(a - m);
        }
        red[tid] = sm; __syncthreads();
        for (int o = 64; o > 0; o >>= 1) { if (tid < o) red[tid] += red[tid + o]; __syncthreads(); }
        const float inv_s = 1.f / red[0]; __syncthreads();
        // pass 3: weighted aggregation; thread tid owns output dim tid
        float acc = 0.f;
        for (int base = 0; base < deg; base += 128) {
            int cnt = deg - base; if (cnt > 128) cnt = 128;
            if (tid < cnt) {
                int sn = srcv[eidx[start + base + tid]];
                float a = asrc[sn * 3 + hd] + adn;
                a = a >= 0.f ? a : NEG * a;
                s_sc[tid] = __expf(a - m) * inv_s;
                s_src[tid] = sn;
            }
            __syncthreads();
            for (int j = 0; j < cnt; j++)
                acc += s_sc[j] * wv[(size_t)s_src[j] * 384 + hd * 128 + tid];
            __syncthreads();
        }
        agg[(size_t)n * 384 + hd * 128 + tid] = acc;
    }
}

// ---------------------------------------------------------------------------
// LN epilogue: x = hcur + (deg>0 ? res : 0); LayerNorm; ReLU; readout accumulate
// ---------------------------------------------------------------------------
__global__ void ln_epilogue(const float* __restrict__ res, const int* __restrict__ deg,
                            const float* __restrict__ gamma, const float* __restrict__ beta,
                            const int* __restrict__ gid, float* __restrict__ hcur,
                            float* __restrict__ reado) {
    int n = blockIdx.x, tid = threadIdx.x;
    __shared__ float red[128];
    float x = hcur[(size_t)n * Hh + tid];
    if (deg[n] > 0) x += res[(size_t)n * Hh + tid];
    red[tid] = x; __syncthreads();
    for (int o = 64; o > 0; o >>= 1) { if (tid < o) red[tid] += red[tid + o]; __syncthreads(); }
    float mu = red[0] * (1.f / 128.f); __syncthreads();
    float d = x - mu;
    red[tid] = d * d; __syncthreads();
    for (int o = 64; o > 0; o >>= 1) { if (tid < o) red[tid] += red[tid + o]; __syncthreads(); }
    float var = red[0] * (1.f / 128.f);
    float y = d * rsqrtf(var + EPS) * gamma[tid] + beta[tid];
    y = fmaxf(y, 0.f);
    hcur[(size_t)n * Hh + tid] = y;
    atomicAdd(&reado[(size_t)gid[n] * Hh + tid], y);
}

// ---------------------------------------------------------------------------
// GRU layer 0: input [B,3,128] (readouts/counts), bidirectional, hidden 128.
// One block per batch element; thread t owns hidden unit t.
// ---------------------------------------------------------------------------
__global__ __launch_bounds__(128) void gru_layer0(const float* __restrict__ reado,
                                                  const int* __restrict__ gcnt,
                                                  const float* __restrict__ Wih,
                                                  const float* __restrict__ Whh,
                                                  const float* __restrict__ bih,
                                                  const float* __restrict__ bhh,
                                                  float* __restrict__ y0,
                                                  float* __restrict__ fin) {
    const int b = blockIdx.x, tid = threadIdx.x;
    __shared__ float xb[3][128];
    __shared__ float hs[128];
    float invc = 1.f / fmaxf((float)gcnt[b], 1.f);
    for (int t = 0; t < 3; t++)
        xb[t][tid] = reado[(size_t)t * Bb * Hh + (size_t)b * Hh + tid] * invc;
    for (int dir = 0; dir < 2; dir++) {
        const float* Wi = Wih + (size_t)dir * 384 * 128;
        const float* Wh = Whh + (size_t)dir * 384 * 128;
        const float* bi = bih + dir * 384;
        const float* bh = bhh + dir * 384;
        __syncthreads();
        hs[tid] = 0.f;
        float hreg = 0.f;
        __syncthreads();
        for (int step = 0; step < 3; step++) {
            int t = dir ? 2 - step : step;
            float gir = bi[tid], giz = bi[tid + 128], gin = bi[tid + 256];
            float ghr = bh[tid], ghz = bh[tid + 128], ghn = bh[tid + 256];
            const float* wir = Wi + (size_t)tid * 128;
            const float* wiz = Wi + (size_t)(tid + 128) * 128;
            const float* win = Wi + (size_t)(tid + 256) * 128;
            const float* whr = Wh + (size_t)tid * 128;
            const float* whz = Wh + (size_t)(tid + 128) * 128;
            const float* whn = Wh + (size_t)(tid + 256) * 128;
            for (int k = 0; k < 128; k++) {
                float xv = xb[t][k], hv = hs[k];
                gir += wir[k] * xv; giz += wiz[k] * xv; gin += win[k] * xv;
                ghr += whr[k] * hv; ghz += whz[k] * hv; ghn += whn[k] * hv;
            }
            float r = 1.f / (1.f + __expf(-(gir + ghr)));
            float z = 1.f / (1.f + __expf(-(giz + ghz)));
            float nn2 = tanhf(gin + r * ghn);
            hreg = (1.f - z) * nn2 + z * hreg;
            __syncthreads();
            hs[tid] = hreg;
            y0[(size_t)b * 768 + t * 256 + dir * 128 + tid] = hreg;
            __syncthreads();
        }
        fin[(size_t)dir * Bb * Hh + (size_t)b * Hh + tid] = hreg;
    }
}

// GRU layer 1: input [B,3,256], bidirectional, hidden 128.
__global__ __launch_bounds__(128) void gru_layer1(const float* __restrict__ y0,
                                                  const float* __restrict__ Wih,
                                                  const float* __restrict__ Whh,
                                                  const float* __restrict__ bih,
                                                  const float* __restrict__ bhh,
                                                  float* __restrict__ fin) {
    const int b = blockIdx.x, tid = threadIdx.x;
    __shared__ float xb[3][256];
    __shared__ float hs[128];
    for (int t = 0; t < 3; t++) {
        xb[t][tid]       = y0[(size_t)b * 768 + t * 256 + tid];
        xb[t][tid + 128] = y0[(size_t)b * 768 + t * 256 + 128 + tid];
    }
    for (int dir = 0; dir < 2; dir++) {
        const float* Wi = Wih + (size_t)dir * 384 * 256;
        const float* Wh = Whh + (size_t)dir * 384 * 128;
        const float* bi = bih + dir * 384;
        const float* bh = bhh + dir * 384;
        __syncthreads();
        hs[tid] = 0.f;
        float hreg = 0.f;
        __syncthreads();
        for (int step = 0; step < 3; step++) {
            int t = dir ? 2 - step : step;
            float gir = bi[tid], giz = bi[tid + 128], gin = bi[tid + 256];
            float ghr = bh[tid], ghz = bh[tid + 128], ghn = bh[tid + 256];
            const float* wir = Wi + (size_t)tid * 256;
            const float* wiz = Wi + (size_t)(tid + 128) * 256;
            const float* win = Wi + (size_t)(tid + 256) * 256;
            const float* whr = Wh + (size_t)tid * 128;
            const float* whz = Wh + (size_t)(tid + 128) * 128;
            const float* whn = Wh + (size_t)(tid + 256) * 128;
            for (int k = 0; k < 256; k++) {
                float xv = xb[t][k];
                gir += wir[k] * xv; giz += wiz[k] * xv; gin += win[k] * xv;
            }
            for (int k = 0; k < 128; k++) {
                float hv = hs[k];
                ghr += whr[k] * hv; ghz += whz[k] * hv; ghn += whn[k] * hv;
            }
            float r = 1.f / (1.f + __expf(-(gir + ghr)));
            float z = 1.f / (1.f + __expf(-(giz + ghz)));
            float nn2 = tanhf(gin + r * ghn);
            hreg = (1.f - z) * nn2 + z * hreg;
            __syncthreads();
            hs[tid] = hreg;
            __syncthreads();
        }
        fin[(size_t)(2 + dir) * Bb * Hh + (size_t)b * Hh + tid] = hreg;
    }
}

__global__ void final_mean(const float* __restrict__ fin, float* __restrict__ out) {
    int b = blockIdx.x, tid = threadIdx.x;
    const size_t s = (size_t)Bb * Hh;
    out[(size_t)b * Hh + tid] = 0.25f * (fin[b * Hh + tid] + fin[s + b * Hh + tid] +
                                         fin[2 * s + b * Hh + tid] + fin[3 * s + b * Hh + tid]);
}

// ---------------------------------------------------------------------------
extern "C" void kernel_launch(void* const* d_in, const int* in_sizes, int n_in,
                              void* d_out, int out_size, void* d_ws, size_t ws_size,
                              hipStream_t stream) {
    const float* h      = (const float*)d_in[0];
    const int*   wid    = (const int*)d_in[1];
    const int*   src    = (const int*)d_in[2];
    const int*   dst    = (const int*)d_in[3];
    const int*   gid    = (const int*)d_in[4];
    const float* projW  = (const float*)d_in[5];
    const float* projB  = (const float*)d_in[6];
    const float* convWn = (const float*)d_in[7];
    const float* convBn = (const float*)d_in[8];
    const float* convAtt= (const float*)d_in[9];
    const float* convWs = (const float*)d_in[10];
    const float* convB  = (const float*)d_in[11];
    const float* convG  = (const float*)d_in[12];
    const float* convBe = (const float*)d_in[13];
    const float* Wih0   = (const float*)d_in[14];
    const float* Whh0   = (const float*)d_in[15];
    const float* bih0   = (const float*)d_in[16];
    const float* bhh0   = (const float*)d_in[17];
    const float* Wih1   = (const float*)d_in[18];
    const float* Whh1   = (const float*)d_in[19];
    const float* bih1   = (const float*)d_in[20];
    const float* bhh1   = (const float*)d_in[21];
    float* out = (float*)d_out;

    char* p = (char*)d_ws;
    auto alloc_f = [&](size_t n) { float* r = (float*)p; p += n * sizeof(float); return r; };
    auto alloc_i = [&](size_t n) { int* r = (int*)p; p += n * sizeof(int); return r; };
    float* hcur  = alloc_f((size_t)Nn * Hh);       // 10.2 MB
    float* wv    = alloc_f((size_t)Nn * 384);      // 30.7 MB
    float* agg   = alloc_f((size_t)Nn * 384);      // 30.7 MB
    float* res   = alloc_f((size_t)Nn * Hh);       // 10.2 MB
    float* asrc  = alloc_f((size_t)Nn * 3);
    float* adst  = alloc_f((size_t)Nn * 3);
    float* reado = alloc_f((size_t)3 * Bb * Hh);
    float* y0    = alloc_f((size_t)Bb * 3 * 256);
    float* fin   = alloc_f((size_t)4 * Bb * Hh);
    int* deg  = alloc_i(Nn);
    int* offs = alloc_i(Nn + 1);
    int* cur  = alloc_i(Nn);
    int* eidx = alloc_i(Ee);
    int* gcnt = alloc_i(Bb);

    // zero-init accumulators (ws is poisoned 0xAA before every launch)
    hipMemsetAsync(reado, 0, (size_t)3 * Bb * Hh * sizeof(float), stream);
    hipMemsetAsync(deg, 0, Nn * sizeof(int), stream);
    hipMemsetAsync(gcnt, 0, Bb * sizeof(int), stream);

    // CSR over dst (identical for both GAT layers)
    hist_dst<<<1250, 256, 0, stream>>>(dst, deg);
    scan_offsets<<<1, 1024, 0, stream>>>(deg, offs, cur);
    fill_csr<<<1250, 256, 0, stream>>>(dst, cur, eidx);

    // projection: hcur = onehot(wid)@Wp + h@Wp[V:] + b
    gemm_f32<<<dim3(Hh / 64, (Nn + 127) / 128), 256, 0, stream>>>(
        h, projW + (size_t)Vv * Hh, nullptr, res, Nn, Hh, Hh);
    proj_epilogue<<<Nn, 128, 0, stream>>>(res, projW, projB, wid, gid, hcur, reado, gcnt);

    for (int l = 0; l < 2; l++) {
        gemm_f32<<<dim3(384 / 64, (Nn + 127) / 128), 256, 0, stream>>>(
            hcur, convWn + (size_t)l * Hh * 384, convBn + l * 384, wv, Nn, 384, Hh);
        att_dots<<<Nn, 128, 0, stream>>>(wv, convAtt + (size_t)l * 3 * 256, asrc, adst);
        gat_aggregate<<<Nn, 128, 0, stream>>>(wv, asrc, adst, offs, eidx, src, agg);
        gemm_f32<<<dim3(Hh / 64, (Nn + 127) / 128), 256, 0, stream>>>(
            agg, convWs + (size_t)l * 384 * Hh, convB + l * Hh, res, Nn, Hh, 384);
        ln_epilogue<<<Nn, 128, 0, stream>>>(res, deg, convG + l * Hh, convBe + l * Hh,
                                            gid, hcur, reado + (size_t)(l + 1) * Bb * Hh);
    }

    gru_layer0<<<Bb, 128, 0, stream>>>(reado, gcnt, Wih0, Whh0, bih0, bhh0, y0, fin);
    gru_layer1<<<Bb, 128, 0, stream>>>(y0, Wih1, Whh1, bih1, bhh1, fin);
    final_mean<<<Bb, 128, 0, stream>>>(fin, out);
}

// Round 2
// 1009.281 us; speedup vs baseline: 1.0634x; 1.0634x over previous
//
#include <hip/hip_runtime.h>
#include <cstddef>

// Problem constants (from reference)
static constexpr int Nn    = 20000;
static constexpr int Ee    = 320000;
static constexpr int Vv    = 100;
static constexpr int Hh    = 128;
static constexpr int HEADS = 3;
static constexpr int Bb    = 200;
static constexpr float NEG = 0.2f;
static constexpr float EPS = 1e-5f;

typedef short bf16x8 __attribute__((ext_vector_type(8)));
typedef float f32x4  __attribute__((ext_vector_type(4)));

__device__ inline unsigned short bf16_rne(float x) {
    unsigned u = __builtin_bit_cast(unsigned, x);
    u += 0x7FFFu + ((u >> 16) & 1u);
    return (unsigned short)(u >> 16);
}
__device__ inline float bf16_f(unsigned short h) {
    unsigned u = ((unsigned)h) << 16;
    return __builtin_bit_cast(float, u);
}

// ---------------------------------------------------------------------------
// CSR build: histogram over dst, single-block scan, fill
// ---------------------------------------------------------------------------
__global__ void hist_dst(const int* __restrict__ dst, int* __restrict__ deg) {
    for (int i = blockIdx.x * blockDim.x + threadIdx.x; i < Ee; i += gridDim.x * blockDim.x)
        atomicAdd(&deg[dst[i]], 1);
}

__global__ __launch_bounds__(1024) void scan_offsets(const int* __restrict__ deg,
                                                     int* __restrict__ offs,
                                                     int* __restrict__ cur) {
    __shared__ int sums[1024];
    const int tid = threadIdx.x;
    const int per = (Nn + 1023) >> 10;          // 20
    int begin = tid * per;
    int end = begin + per; if (end > Nn) end = Nn;
    if (begin > Nn) begin = Nn;
    int s = 0;
    for (int i = begin; i < end; i++) s += deg[i];
    sums[tid] = s;
    __syncthreads();
    for (int off = 1; off < 1024; off <<= 1) {
        int v = (tid >= off) ? sums[tid - off] : 0;
        __syncthreads();
        sums[tid] += v;
        __syncthreads();
    }
    int run = sums[tid] - s;                    // exclusive prefix
    for (int i = begin; i < end; i++) {
        offs[i] = run; cur[i] = run;
        run += deg[i];
    }
    if (end == Nn) offs[Nn] = run;
}

__global__ void fill_csr(const int* __restrict__ dst, int* __restrict__ cur,
                         int* __restrict__ eidx) {
    for (int i = blockIdx.x * blockDim.x + threadIdx.x; i < Ee; i += gridDim.x * blockDim.x) {
        int p = atomicAdd(&cur[dst[i]], 1);
        eidx[p] = i;
    }
}

// ---------------------------------------------------------------------------
// Weight prep: B[K][N] fp32 -> Bt_hi/Bt_lo [N][K] bf16 (split hi+lo)
// ---------------------------------------------------------------------------
__global__ void wprep(const float* __restrict__ B, int K, int N,
                      unsigned short* __restrict__ Bth, unsigned short* __restrict__ Btl) {
    int idx = blockIdx.x * blockDim.x + threadIdx.x;
    if (idx >= K * N) return;
    int k = idx / N, n = idx % N;
    float v = B[idx];
    unsigned short h = bf16_rne(v);
    unsigned short l = bf16_rne(v - bf16_f(h));
    Bth[(size_t)n * K + k] = h;
    Btl[(size_t)n * K + k] = l;
}

// ---------------------------------------------------------------------------
// Split-bf16 MFMA GEMM: C[M,N] = A[M,K](fp32) @ B + bias
// B supplied as transposed hi/lo bf16: Bt[N][K].
// C ~= Ahi*Bhi + Ahi*Blo + Alo*Bhi  (fp32 accumulate, ~2^-17 relative error)
// BM=128, BN=64, BK=32; 256 threads = 4 waves (2x2); wave tile 64x32 (4x2 MFMA).
// Requires K%32==0, N%64==0.
// ---------------------------------------------------------------------------
__global__ __launch_bounds__(256) void gemm_mfma(const float* __restrict__ A,
                                                 const unsigned short* __restrict__ Bth,
                                                 const unsigned short* __restrict__ Btl,
                                                 const float* __restrict__ bias,
                                                 float* __restrict__ C,
                                                 int M, int N, int K) {
    __shared__ unsigned short As_hi[128][40];   // [m][k], pad 32->40 (16B-aligned rows)
    __shared__ unsigned short As_lo[128][40];
    __shared__ unsigned short Bs_hi[64][40];    // [n][k]
    __shared__ unsigned short Bs_lo[64][40];
    const int tid  = threadIdx.x;
    const int row0 = blockIdx.y * 128;
    const int col0 = blockIdx.x * 64;
    const int w    = tid >> 6;       // wave 0..3
    const int wm   = w >> 1;         // 0..1 (M)
    const int wn   = w & 1;          // 0..1 (N)
    const int L    = tid & 63;
    const int lrow = L & 15;
    const int lq   = L >> 4;         // 0..3

    f32x4 acc[4][2];
#pragma unroll
    for (int i = 0; i < 4; i++)
#pragma unroll
        for (int j = 0; j < 2; j++) acc[i][j] = (f32x4){0.f, 0.f, 0.f, 0.f};

    for (int kb = 0; kb < K; kb += 32) {
        // ---- stage A (fp32 -> hi/lo bf16), 128 x 32 ----
#pragma unroll
        for (int it = 0; it < 4; it++) {
            int idx = tid + it * 256;          // 0..1023
            int m  = idx >> 3;                 // 0..127
            int kq = (idx & 7) * 4;            // 0,4,...,28
            int gr = row0 + m;
            float4 v = make_float4(0.f, 0.f, 0.f, 0.f);
            if (gr < M) v = *(const float4*)(A + (size_t)gr * K + kb + kq);
            unsigned short h0 = bf16_rne(v.x), h1 = bf16_rne(v.y),
                           h2 = bf16_rne(v.z), h3 = bf16_rne(v.w);
            short4 hi4 = make_short4((short)h0, (short)h1, (short)h2, (short)h3);
            short4 lo4 = make_short4((short)bf16_rne(v.x - bf16_f(h0)),
                                     (short)bf16_rne(v.y - bf16_f(h1)),
                                     (short)bf16_rne(v.z - bf16_f(h2)),
                                     (short)bf16_rne(v.w - bf16_f(h3)));
            *(short4*)&As_hi[m][kq] = hi4;
            *(short4*)&As_lo[m][kq] = lo4;
        }
        // ---- stage B^T (already bf16), 64 x 32 ----
        {
            int n  = tid >> 2;                 // 0..63
            int kq = (tid & 3) * 8;            // 0,8,16,24
            const unsigned short* sh = Bth + (size_t)(col0 + n) * K + kb + kq;
            const unsigned short* sl = Btl + (size_t)(col0 + n) * K + kb + kq;
            *(float4*)&Bs_hi[n][kq] = *(const float4*)sh;
            *(float4*)&Bs_lo[n][kq] = *(const float4*)sl;
        }
        __syncthreads();
        // ---- fragments + MFMA ----
        bf16x8 ah[4], al[4], bh[2], bl[2];
#pragma unroll
        for (int mi = 0; mi < 4; mi++) {
            int r = wm * 64 + mi * 16 + lrow;
            ah[mi] = *(const bf16x8*)&As_hi[r][lq * 8];
            al[mi] = *(const bf16x8*)&As_lo[r][lq * 8];
        }
#pragma unroll
        for (int ni = 0; ni < 2; ni++) {
            int r = wn * 32 + ni * 16 + lrow;
            bh[ni] = *(const bf16x8*)&Bs_hi[r][lq * 8];
            bl[ni] = *(const bf16x8*)&Bs_lo[r][lq * 8];
        }
#pragma unroll
        for (int mi = 0; mi < 4; mi++)
#pragma unroll
            for (int ni = 0; ni < 2; ni++) {
                acc[mi][ni] = __builtin_amdgcn_mfma_f32_16x16x32_bf16(ah[mi], bh[ni], acc[mi][ni], 0, 0, 0);
                acc[mi][ni] = __builtin_amdgcn_mfma_f32_16x16x32_bf16(ah[mi], bl[ni], acc[mi][ni], 0, 0, 0);
                acc[mi][ni] = __builtin_amdgcn_mfma_f32_16x16x32_bf16(al[mi], bh[ni], acc[mi][ni], 0, 0, 0);
            }
        __syncthreads();
    }
    // ---- epilogue: C/D layout col=lane&15, row=(lane>>4)*4+reg ----
#pragma unroll
    for (int mi = 0; mi < 4; mi++)
#pragma unroll
        for (int ni = 0; ni < 2; ni++) {
            int col = col0 + wn * 32 + ni * 16 + lrow;
            float bb = bias ? bias[col] : 0.f;
#pragma unroll
            for (int r = 0; r < 4; r++) {
                int row = row0 + wm * 64 + mi * 16 + lq * 4 + r;
                if (row < M) C[(size_t)row * N + col] = acc[mi][ni][r] + bb;
            }
        }
}

// ---------------------------------------------------------------------------
// proj epilogue: hcur = gemm_out + projW[wid] + projB; readout0 accumulate
// ---------------------------------------------------------------------------
__global__ void proj_epilogue(const float* __restrict__ res, const float* __restrict__ projW,
                              const float* __restrict__ projB, const int* __restrict__ wid,
                              const int* __restrict__ gid, float* __restrict__ hcur,
                              float* __restrict__ reado, int* __restrict__ gcnt) {
    int n = blockIdx.x, tid = threadIdx.x;
    float v = res[(size_t)n * Hh + tid] + projW[(size_t)wid[n] * Hh + tid] + projB[tid];
    hcur[(size_t)n * Hh + tid] = v;
    atomicAdd(&reado[(size_t)gid[n] * Hh + tid], v);
    if (tid == 0) atomicAdd(&gcnt[gid[n]], 1);
}

// ---------------------------------------------------------------------------
// per-node attention dots: asrc[n,h] = <wv[n,h,:], att[h,:128]>, adst with att[h,128:]
// ---------------------------------------------------------------------------
__global__ void att_dots(const float* __restrict__ wv, const float* __restrict__ att,
                         float* __restrict__ asrc, float* __restrict__ adst) {
    int n = blockIdx.x, tid = threadIdx.x;
    __shared__ float red[2][128];
    for (int hd = 0; hd < HEADS; hd++) {
        float w = wv[(size_t)n * 384 + hd * 128 + tid];
        red[0][tid] = w * att[hd * 256 + tid];
        red[1][tid] = w * att[hd * 256 + 128 + tid];
        __syncthreads();
        for (int o = 64; o > 0; o >>= 1) {
            if (tid < o) { red[0][tid] += red[0][tid + o]; red[1][tid] += red[1][tid + o]; }
            __syncthreads();
        }
        if (tid == 0) { asrc[n * 3 + hd] = red[0][0]; adst[n * 3 + hd] = red[1][0]; }
        __syncthreads();
    }
}

// ---------------------------------------------------------------------------
// Per-dst-node softmax attention + aggregation (no atomics; CSR)
// ---------------------------------------------------------------------------
__global__ __launch_bounds__(128) void gat_aggregate(const float* __restrict__ wv,
                                                     const float* __restrict__ asrc,
                                                     const float* __restrict__ adst,
                                                     const int* __restrict__ offs,
                                                     const int* __restrict__ eidx,
                                                     const int* __restrict__ srcv,
                                                     float* __restrict__ agg) {
    const int n = blockIdx.x, tid = threadIdx.x;
    const int start = offs[n], end = offs[n + 1];
    const int deg = end - start;
    if (deg == 0) {
        for (int j = tid; j < 384; j += 128) agg[(size_t)n * 384 + j] = 0.f;
        return;
    }
    __shared__ float red[128];
    __shared__ float s_sc[128];
    __shared__ int   s_src[128];
    for (int hd = 0; hd < HEADS; hd++) {
        const float adn = adst[n * 3 + hd];
        float mx = -INFINITY;
        for (int i = tid; i < deg; i += 128) {
            int sn = srcv[eidx[start + i]];
            float a = asrc[sn * 3 + hd] + adn;
            a = a >= 0.f ? a : NEG * a;
            mx = fmaxf(mx, a);
        }
        red[tid] = mx; __syncthreads();
        for (int o = 64; o > 0; o >>= 1) { if (tid < o) red[tid] = fmaxf(red[tid], red[tid + o]); __syncthreads(); }
        const float m = red[0]; __syncthreads();
        float sm = 0.f;
        for (int i = tid; i < deg; i += 128) {
            int sn = srcv[eidx[start + i]];
            float a = asrc[sn * 3 + hd] + adn;
            a = a >= 0.f ? a : NEG * a;
            sm += __expf(a - m);
        }
        red[tid] = sm; __syncthreads();
        for (int o = 64; o > 0; o >>= 1) { if (tid < o) red[tid] += red[tid + o]; __syncthreads(); }
        const float inv_s = 1.f / red[0]; __syncthreads();
        float acc = 0.f;
        for (int base = 0; base < deg; base += 128) {
            int cnt = deg - base; if (cnt > 128) cnt = 128;
            if (tid < cnt) {
                int sn = srcv[eidx[start + base + tid]];
                float a = asrc[sn * 3 + hd] + adn;
                a = a >= 0.f ? a : NEG * a;
                s_sc[tid] = __expf(a - m) * inv_s;
                s_src[tid] = sn;
            }
            __syncthreads();
            for (int j = 0; j < cnt; j++)
                acc += s_sc[j] * wv[(size_t)s_src[j] * 384 + hd * 128 + tid];
            __syncthreads();
        }
        agg[(size_t)n * 384 + hd * 128 + tid] = acc;
    }
}

// ---------------------------------------------------------------------------
// LN epilogue: x = hcur + (deg>0 ? res : 0); LayerNorm; ReLU; readout accumulate
// ---------------------------------------------------------------------------
__global__ void ln_epilogue(const float* __restrict__ res, const int* __restrict__ deg,
                            const float* __restrict__ gamma, const float* __restrict__ beta,
                            const int* __restrict__ gid, float* __restrict__ hcur,
                            float* __restrict__ reado) {
    int n = blockIdx.x, tid = threadIdx.x;
    __shared__ float red[128];
    float x = hcur[(size_t)n * Hh + tid];
    if (deg[n] > 0) x += res[(size_t)n * Hh + tid];
    red[tid] = x; __syncthreads();
    for (int o = 64; o > 0; o >>= 1) { if (tid < o) red[tid] += red[tid + o]; __syncthreads(); }
    float mu = red[0] * (1.f / 128.f); __syncthreads();
    float d = x - mu;
    red[tid] = d * d; __syncthreads();
    for (int o = 64; o > 0; o >>= 1) { if (tid < o) red[tid] += red[tid + o]; __syncthreads(); }
    float var = red[0] * (1.f / 128.f);
    float y = d * rsqrtf(var + EPS) * gamma[tid] + beta[tid];
    y = fmaxf(y, 0.f);
    hcur[(size_t)n * Hh + tid] = y;
    atomicAdd(&reado[(size_t)gid[n] * Hh + tid], y);
}

// ---------------------------------------------------------------------------
// GRU layer 0: input [B,3,128], bidirectional, hidden 128.
// ---------------------------------------------------------------------------
__global__ __launch_bounds__(128) void gru_layer0(const float* __restrict__ reado,
                                                  const int* __restrict__ gcnt,
                                                  const float* __restrict__ Wih,
                                                  const float* __restrict__ Whh,
                                                  const float* __restrict__ bih,
                                                  const float* __restrict__ bhh,
                                                  float* __restrict__ y0,
                                                  float* __restrict__ fin) {
    const int b = blockIdx.x, tid = threadIdx.x;
    __shared__ float xb[3][128];
    __shared__ float hs[128];
    float invc = 1.f / fmaxf((float)gcnt[b], 1.f);
    for (int t = 0; t < 3; t++)
        xb[t][tid] = reado[(size_t)t * Bb * Hh + (size_t)b * Hh + tid] * invc;
    for (int dir = 0; dir < 2; dir++) {
        const float* Wi = Wih + (size_t)dir * 384 * 128;
        const float* Wh = Whh + (size_t)dir * 384 * 128;
        const float* bi = bih + dir * 384;
        const float* bh = bhh + dir * 384;
        __syncthreads();
        hs[tid] = 0.f;
        float hreg = 0.f;
        __syncthreads();
        for (int step = 0; step < 3; step++) {
            int t = dir ? 2 - step : step;
            float gir = bi[tid], giz = bi[tid + 128], gin = bi[tid + 256];
            float ghr = bh[tid], ghz = bh[tid + 128], ghn = bh[tid + 256];
            const float* wir = Wi + (size_t)tid * 128;
            const float* wiz = Wi + (size_t)(tid + 128) * 128;
            const float* win = Wi + (size_t)(tid + 256) * 128;
            const float* whr = Wh + (size_t)tid * 128;
            const float* whz = Wh + (size_t)(tid + 128) * 128;
            const float* whn = Wh + (size_t)(tid + 256) * 128;
            for (int k = 0; k < 128; k++) {
                float xv = xb[t][k], hv = hs[k];
                gir += wir[k] * xv; giz += wiz[k] * xv; gin += win[k] * xv;
                ghr += whr[k] * hv; ghz += whz[k] * hv; ghn += whn[k] * hv;
            }
            float r = 1.f / (1.f + __expf(-(gir + ghr)));
            float z = 1.f / (1.f + __expf(-(giz + ghz)));
            float nn2 = tanhf(gin + r * ghn);
            hreg = (1.f - z) * nn2 + z * hreg;
            __syncthreads();
            hs[tid] = hreg;
            y0[(size_t)b * 768 + t * 256 + dir * 128 + tid] = hreg;
            __syncthreads();
        }
        fin[(size_t)dir * Bb * Hh + (size_t)b * Hh + tid] = hreg;
    }
}

// GRU layer 1: input [B,3,256], bidirectional, hidden 128.
__global__ __launch_bounds__(128) void gru_layer1(const float* __restrict__ y0,
                                                  const float* __restrict__ Wih,
                                                  const float* __restrict__ Whh,
                                                  const float* __restrict__ bih,
                                                  const float* __restrict__ bhh,
                                                  float* __restrict__ fin) {
    const int b = blockIdx.x, tid = threadIdx.x;
    __shared__ float xb[3][256];
    __shared__ float hs[128];
    for (int t = 0; t < 3; t++) {
        xb[t][tid]       = y0[(size_t)b * 768 + t * 256 + tid];
        xb[t][tid + 128] = y0[(size_t)b * 768 + t * 256 + 128 + tid];
    }
    for (int dir = 0; dir < 2; dir++) {
        const float* Wi = Wih + (size_t)dir * 384 * 256;
        const float* Wh = Whh + (size_t)dir * 384 * 128;
        const float* bi = bih + dir * 384;
        const float* bh = bhh + dir * 384;
        __syncthreads();
        hs[tid] = 0.f;
        float hreg = 0.f;
        __syncthreads();
        for (int step = 0; step < 3; step++) {
            int t = dir ? 2 - step : step;
            float gir = bi[tid], giz = bi[tid + 128], gin = bi[tid + 256];
            float ghr = bh[tid], ghz = bh[tid + 128], ghn = bh[tid + 256];
            const float* wir = Wi + (size_t)tid * 256;
            const float* wiz = Wi + (size_t)(tid + 128) * 256;
            const float* win = Wi + (size_t)(tid + 256) * 256;
            const float* whr = Wh + (size_t)tid * 128;
            const float* whz = Wh + (size_t)(tid + 128) * 128;
            const float* whn = Wh + (size_t)(tid + 256) * 128;
            for (int k = 0; k < 256; k++) {
                float xv = xb[t][k];
                gir += wir[k] * xv; giz += wiz[k] * xv; gin += win[k] * xv;
            }
            for (int k = 0; k < 128; k++) {
                float hv = hs[k];
                ghr += whr[k] * hv; ghz += whz[k] * hv; ghn += whn[k] * hv;
            }
            float r = 1.f / (1.f + __expf(-(gir + ghr)));
            float z = 1.f / (1.f + __expf(-(giz + ghz)));
            float nn2 = tanhf(gin + r * ghn);
            hreg = (1.f - z) * nn2 + z * hreg;
            __syncthreads();
            hs[tid] = hreg;
            __syncthreads();
        }
        fin[(size_t)(2 + dir) * Bb * Hh + (size_t)b * Hh + tid] = hreg;
    }
}

__global__ void final_mean(const float* __restrict__ fin, float* __restrict__ out) {
    int b = blockIdx.x, tid = threadIdx.x;
    const size_t s = (size_t)Bb * Hh;
    out[(size_t)b * Hh + tid] = 0.25f * (fin[b * Hh + tid] + fin[s + b * Hh + tid] +
                                         fin[2 * s + b * Hh + tid] + fin[3 * s + b * Hh + tid]);
}

// ---------------------------------------------------------------------------
extern "C" void kernel_launch(void* const* d_in, const int* in_sizes, int n_in,
                              void* d_out, int out_size, void* d_ws, size_t ws_size,
                              hipStream_t stream) {
    const float* h      = (const float*)d_in[0];
    const int*   wid    = (const int*)d_in[1];
    const int*   src    = (const int*)d_in[2];
    const int*   dst    = (const int*)d_in[3];
    const int*   gid    = (const int*)d_in[4];
    const float* projW  = (const float*)d_in[5];
    const float* projB  = (const float*)d_in[6];
    const float* convWn = (const float*)d_in[7];
    const float* convBn = (const float*)d_in[8];
    const float* convAtt= (const float*)d_in[9];
    const float* convWs = (const float*)d_in[10];
    const float* convB  = (const float*)d_in[11];
    const float* convG  = (const float*)d_in[12];
    const float* convBe = (const float*)d_in[13];
    const float* Wih0   = (const float*)d_in[14];
    const float* Whh0   = (const float*)d_in[15];
    const float* bih0   = (const float*)d_in[16];
    const float* bhh0   = (const float*)d_in[17];
    const float* Wih1   = (const float*)d_in[18];
    const float* Whh1   = (const float*)d_in[19];
    const float* bih1   = (const float*)d_in[20];
    const float* bhh1   = (const float*)d_in[21];
    float* out = (float*)d_out;

    char* p = (char*)d_ws;
    auto alloc_f = [&](size_t n) { float* r = (float*)p; p += n * sizeof(float); return r; };
    auto alloc_i = [&](size_t n) { int* r = (int*)p; p += n * sizeof(int); return r; };
    auto alloc_s = [&](size_t n) { unsigned short* r = (unsigned short*)p; p += n * sizeof(unsigned short); return r; };
    float* hcur  = alloc_f((size_t)Nn * Hh);       // 10.2 MB
    float* wv    = alloc_f((size_t)Nn * 384);      // 30.7 MB
    float* agg   = alloc_f((size_t)Nn * 384);      // 30.7 MB
    float* res   = alloc_f((size_t)Nn * Hh);       // 10.2 MB
    float* asrc  = alloc_f((size_t)Nn * 3);
    float* adst  = alloc_f((size_t)Nn * 3);
    float* reado = alloc_f((size_t)3 * Bb * Hh);
    float* y0    = alloc_f((size_t)Bb * 3 * 256);
    float* fin   = alloc_f((size_t)4 * Bb * Hh);
    int* deg  = alloc_i(Nn);
    int* offs = alloc_i(Nn + 1);
    int* cur  = alloc_i(Nn);
    int* eidx = alloc_i(Ee);
    int* gcnt = alloc_i(Bb);
    // split-bf16 transposed weights
    unsigned short* pBth  = alloc_s(128 * 128);
    unsigned short* pBtl  = alloc_s(128 * 128);
    unsigned short* WnTh[2] = { alloc_s(384 * 128), alloc_s(384 * 128) };
    unsigned short* WnTl[2] = { alloc_s(384 * 128), alloc_s(384 * 128) };
    unsigned short* WsTh[2] = { alloc_s(128 * 384), alloc_s(128 * 384) };
    unsigned short* WsTl[2] = { alloc_s(128 * 384), alloc_s(128 * 384) };

    hipMemsetAsync(reado, 0, (size_t)3 * Bb * Hh * sizeof(float), stream);
    hipMemsetAsync(deg, 0, Nn * sizeof(int), stream);
    hipMemsetAsync(gcnt, 0, Bb * sizeof(int), stream);

    // CSR over dst (identical for both GAT layers)
    hist_dst<<<1250, 256, 0, stream>>>(dst, deg);
    scan_offsets<<<1, 1024, 0, stream>>>(deg, offs, cur);
    fill_csr<<<1250, 256, 0, stream>>>(dst, cur, eidx);

    // weight prep (transpose + hi/lo split)
    wprep<<<(128 * 128 + 255) / 256, 256, 0, stream>>>(projW + (size_t)Vv * Hh, 128, 128, pBth, pBtl);
    for (int l = 0; l < 2; l++) {
        wprep<<<(128 * 384 + 255) / 256, 256, 0, stream>>>(convWn + (size_t)l * 128 * 384, 128, 384, WnTh[l], WnTl[l]);
        wprep<<<(384 * 128 + 255) / 256, 256, 0, stream>>>(convWs + (size_t)l * 384 * 128, 384, 128, WsTh[l], WsTl[l]);
    }

    // projection
    gemm_mfma<<<dim3(2, (Nn + 127) / 128), 256, 0, stream>>>(h, pBth, pBtl, nullptr, res, Nn, 128, 128);
    proj_epilogue<<<Nn, 128, 0, stream>>>(res, projW, projB, wid, gid, hcur, reado, gcnt);

    for (int l = 0; l < 2; l++) {
        gemm_mfma<<<dim3(6, (Nn + 127) / 128), 256, 0, stream>>>(
            hcur, WnTh[l], WnTl[l], convBn + l * 384, wv, Nn, 384, 128);
        att_dots<<<Nn, 128, 0, stream>>>(wv, convAtt + (size_t)l * 3 * 256, asrc, adst);
        gat_aggregate<<<Nn, 128, 0, stream>>>(wv, asrc, adst, offs, eidx, src, agg);
        gemm_mfma<<<dim3(2, (Nn + 127) / 128), 256, 0, stream>>>(
            agg, WsTh[l], WsTl[l], convB + l * Hh, res, Nn, 128, 384);
        ln_epilogue<<<Nn, 128, 0, stream>>>(res, deg, convG + l * Hh, convBe + l * Hh,
                                            gid, hcur, reado + (size_t)(l + 1) * Bb * Hh);
    }

    gru_layer0<<<Bb, 128, 0, stream>>>(reado, gcnt, Wih0, Whh0, bih0, bhh0, y0, fin);
    gru_layer1<<<Bb, 128, 0, stream>>>(y0, Wih1, Whh1, bih1, bhh1, fin);
    final_mean<<<Bb, 128, 0, stream>>>(fin, out);
}

// Round 3
// 834.882 us; speedup vs baseline: 1.2856x; 1.2089x over previous
//
#include <hip/hip_runtime.h>
#include <cstddef>

// Problem constants (from reference)
static constexpr int Nn    = 20000;
static constexpr int Ee    = 320000;
static constexpr int Vv    = 100;
static constexpr int Hh    = 128;
static constexpr int HEADS = 3;
static constexpr int Bb    = 200;
static constexpr float NEG = 0.2f;
static constexpr float EPS = 1e-5f;

typedef short bf16x8 __attribute__((ext_vector_type(8)));
typedef float f32x4  __attribute__((ext_vector_type(4)));

__device__ inline unsigned short bf16_rne(float x) {
    unsigned u = __builtin_bit_cast(unsigned, x);
    u += 0x7FFFu + ((u >> 16) & 1u);
    return (unsigned short)(u >> 16);
}
__device__ inline float bf16_f(unsigned short h) {
    unsigned u = ((unsigned)h) << 16;
    return __builtin_bit_cast(float, u);
}
__device__ inline float lrelu(float a) { return a >= 0.f ? a : NEG * a; }

// ---------------------------------------------------------------------------
// CSR build: histogram over dst, single-block scan, fill (stores src ids)
// ---------------------------------------------------------------------------
__global__ void hist_dst(const int* __restrict__ dst, int* __restrict__ deg) {
    for (int i = blockIdx.x * blockDim.x + threadIdx.x; i < Ee; i += gridDim.x * blockDim.x)
        atomicAdd(&deg[dst[i]], 1);
}

__global__ __launch_bounds__(1024) void scan_offsets(const int* __restrict__ deg,
                                                     int* __restrict__ offs,
                                                     int* __restrict__ cur) {
    __shared__ int sums[1024];
    const int tid = threadIdx.x;
    const int per = (Nn + 1023) >> 10;          // 20
    int begin = tid * per;
    int end = begin + per; if (end > Nn) end = Nn;
    if (begin > Nn) begin = Nn;
    int s = 0;
    for (int i = begin; i < end; i++) s += deg[i];
    sums[tid] = s;
    __syncthreads();
    for (int off = 1; off < 1024; off <<= 1) {
        int v = (tid >= off) ? sums[tid - off] : 0;
        __syncthreads();
        sums[tid] += v;
        __syncthreads();
    }
    int run = sums[tid] - s;                    // exclusive prefix
    for (int i = begin; i < end; i++) {
        offs[i] = run; cur[i] = run;
        run += deg[i];
    }
    if (end == Nn) offs[Nn] = run;
}

__global__ void fill_csr(const int* __restrict__ dst, const int* __restrict__ src,
                         int* __restrict__ cur, int* __restrict__ csrc) {
    for (int i = blockIdx.x * blockDim.x + threadIdx.x; i < Ee; i += gridDim.x * blockDim.x) {
        int p = atomicAdd(&cur[dst[i]], 1);
        csrc[p] = src[i];
    }
}

// ---------------------------------------------------------------------------
// Weight prep: B[K][N] fp32 -> Bt_hi/Bt_lo [N][K] bf16 (split hi+lo)
// ---------------------------------------------------------------------------
__global__ void wprep(const float* __restrict__ B, int K, int N,
                      unsigned short* __restrict__ Bth, unsigned short* __restrict__ Btl) {
    int idx = blockIdx.x * blockDim.x + threadIdx.x;
    if (idx >= K * N) return;
    int k = idx / N, n = idx % N;
    float v = B[idx];
    unsigned short h = bf16_rne(v);
    unsigned short l = bf16_rne(v - bf16_f(h));
    Bth[(size_t)n * K + k] = h;
    Btl[(size_t)n * K + k] = l;
}

// ---------------------------------------------------------------------------
// Split-bf16 MFMA GEMM: C[M,N] = A[M,K](fp32) @ B + bias
// B supplied transposed hi/lo bf16: Bt[N][K].
// C ~= Ahi*Bhi + Ahi*Blo + Alo*Bhi  (fp32 accumulate)
// BM=128, BN=128, BK=32; 256 threads = 4 waves (2x2); wave tile 64x64 (4x4 MFMA).
// Requires K%32==0, N%128==0.
// ---------------------------------------------------------------------------
__global__ __launch_bounds__(256) void gemm_mfma(const float* __restrict__ A,
                                                 const unsigned short* __restrict__ Bth,
                                                 const unsigned short* __restrict__ Btl,
                                                 const float* __restrict__ bias,
                                                 float* __restrict__ C,
                                                 int M, int N, int K) {
    __shared__ unsigned short As_hi[128][40];   // [m][k]
    __shared__ unsigned short As_lo[128][40];
    __shared__ unsigned short Bs_hi[128][40];   // [n][k]
    __shared__ unsigned short Bs_lo[128][40];
    const int tid  = threadIdx.x;
    const int row0 = blockIdx.y * 128;
    const int col0 = blockIdx.x * 128;
    const int w    = tid >> 6;       // wave 0..3
    const int wm   = w >> 1;         // 0..1 (M)
    const int wn   = w & 1;          // 0..1 (N)
    const int L    = tid & 63;
    const int lrow = L & 15;
    const int lq   = L >> 4;         // 0..3

    f32x4 acc[4][4];
#pragma unroll
    for (int i = 0; i < 4; i++)
#pragma unroll
        for (int j = 0; j < 4; j++) acc[i][j] = (f32x4){0.f, 0.f, 0.f, 0.f};

    for (int kb = 0; kb < K; kb += 32) {
        // ---- stage A (fp32 -> hi/lo bf16), 128 x 32 ----
#pragma unroll
        for (int it = 0; it < 4; it++) {
            int idx = tid + it * 256;          // 0..1023
            int m  = idx >> 3;                 // 0..127
            int kq = (idx & 7) * 4;            // 0,4,...,28
            int gr = row0 + m;
            float4 v = make_float4(0.f, 0.f, 0.f, 0.f);
            if (gr < M) v = *(const float4*)(A + (size_t)gr * K + kb + kq);
            unsigned short h0 = bf16_rne(v.x), h1 = bf16_rne(v.y),
                           h2 = bf16_rne(v.z), h3 = bf16_rne(v.w);
            short4 hi4 = make_short4((short)h0, (short)h1, (short)h2, (short)h3);
            short4 lo4 = make_short4((short)bf16_rne(v.x - bf16_f(h0)),
                                     (short)bf16_rne(v.y - bf16_f(h1)),
                                     (short)bf16_rne(v.z - bf16_f(h2)),
                                     (short)bf16_rne(v.w - bf16_f(h3)));
            *(short4*)&As_hi[m][kq] = hi4;
            *(short4*)&As_lo[m][kq] = lo4;
        }
        // ---- stage B^T (already bf16), 128 n x 32 k ----
        {
            int n  = tid >> 1;                 // 0..127
            int kh = (tid & 1) * 16;           // 0 or 16
            const unsigned short* sh = Bth + (size_t)(col0 + n) * K + kb + kh;
            const unsigned short* sl = Btl + (size_t)(col0 + n) * K + kb + kh;
            *(float4*)&Bs_hi[n][kh]     = *(const float4*)sh;
            *(float4*)&Bs_hi[n][kh + 8] = *(const float4*)(sh + 8);
            *(float4*)&Bs_lo[n][kh]     = *(const float4*)sl;
            *(float4*)&Bs_lo[n][kh + 8] = *(const float4*)(sl + 8);
        }
        __syncthreads();
        // ---- fragments + MFMA ----
        bf16x8 ah[4], al[4], bh[4], bl[4];
#pragma unroll
        for (int mi = 0; mi < 4; mi++) {
            int r = wm * 64 + mi * 16 + lrow;
            ah[mi] = *(const bf16x8*)&As_hi[r][lq * 8];
            al[mi] = *(const bf16x8*)&As_lo[r][lq * 8];
        }
#pragma unroll
        for (int ni = 0; ni < 4; ni++) {
            int r = wn * 64 + ni * 16 + lrow;
            bh[ni] = *(const bf16x8*)&Bs_hi[r][lq * 8];
            bl[ni] = *(const bf16x8*)&Bs_lo[r][lq * 8];
        }
#pragma unroll
        for (int mi = 0; mi < 4; mi++)
#pragma unroll
            for (int ni = 0; ni < 4; ni++) {
                acc[mi][ni] = __builtin_amdgcn_mfma_f32_16x16x32_bf16(ah[mi], bh[ni], acc[mi][ni], 0, 0, 0);
                acc[mi][ni] = __builtin_amdgcn_mfma_f32_16x16x32_bf16(ah[mi], bl[ni], acc[mi][ni], 0, 0, 0);
                acc[mi][ni] = __builtin_amdgcn_mfma_f32_16x16x32_bf16(al[mi], bh[ni], acc[mi][ni], 0, 0, 0);
            }
        __syncthreads();
    }
    // ---- epilogue: C/D layout col=lane&15, row=(lane>>4)*4+reg ----
#pragma unroll
    for (int mi = 0; mi < 4; mi++)
#pragma unroll
        for (int ni = 0; ni < 4; ni++) {
            int col = col0 + wn * 64 + ni * 16 + lrow;
            float bb = bias ? bias[col] : 0.f;
#pragma unroll
            for (int r = 0; r < 4; r++) {
                int row = row0 + wm * 64 + mi * 16 + lq * 4 + r;
                if (row < M) C[(size_t)row * N + col] = acc[mi][ni][r] + bb;
            }
        }
}

// ---------------------------------------------------------------------------
// proj epilogue: hcur = gemm_out + projW[wid] + projB; readout0 accumulate
// ---------------------------------------------------------------------------
__global__ void proj_epilogue(const float* __restrict__ res, const float* __restrict__ projW,
                              const float* __restrict__ projB, const int* __restrict__ wid,
                              const int* __restrict__ gid, float* __restrict__ hcur,
                              float* __restrict__ reado, int* __restrict__ gcnt) {
    int n = blockIdx.x, tid = threadIdx.x;
    float v = res[(size_t)n * Hh + tid] + projW[(size_t)wid[n] * Hh + tid] + projB[tid];
    hcur[(size_t)n * Hh + tid] = v;
    atomicAdd(&reado[(size_t)gid[n] * Hh + tid], v);
    if (tid == 0) atomicAdd(&gcnt[gid[n]], 1);
}

// ---------------------------------------------------------------------------
// att_dots, one wave per node: ad[n]={asrc0,asrc1,asrc2,_}, add[n]={adst0,...}
// ---------------------------------------------------------------------------
__global__ __launch_bounds__(256) void att_dots(const float* __restrict__ wv,
                                                const float* __restrict__ att,
                                                float4* __restrict__ ad,
                                                float4* __restrict__ add) {
    const int wid_g = (blockIdx.x * 256 + threadIdx.x) >> 6;
    const int L = threadIdx.x & 63;
    if (wid_g >= Nn) return;
    const float2* w2 = (const float2*)(wv + (size_t)wid_g * 384);
    float s[3], d[3];
#pragma unroll
    for (int hd = 0; hd < 3; hd++) {
        float2 w = w2[hd * 64 + L];
        float2 as = *(const float2*)(att + hd * 256 + 2 * L);
        float2 at = *(const float2*)(att + hd * 256 + 128 + 2 * L);
        s[hd] = w.x * as.x + w.y * as.y;
        d[hd] = w.x * at.x + w.y * at.y;
    }
#pragma unroll
    for (int o = 32; o > 0; o >>= 1) {
#pragma unroll
        for (int hd = 0; hd < 3; hd++) {
            s[hd] += __shfl_xor(s[hd], o, 64);
            d[hd] += __shfl_xor(d[hd], o, 64);
        }
    }
    if (L == 0) {
        ad[wid_g]  = make_float4(s[0], s[1], s[2], 0.f);
        add[wid_g] = make_float4(d[0], d[1], d[2], 0.f);
    }
}

// ---------------------------------------------------------------------------
// GAT softmax-attention aggregation, one wave per dst node, zero barriers.
// Pass 1: online max/sum of leaky-relu logits (3 heads in registers).
// Pass 2: gather wv[src] rows, broadcast (src,score) via shuffles.
// ---------------------------------------------------------------------------
__global__ __launch_bounds__(256) void gat_aggregate(const float* __restrict__ wv,
                                                     const float4* __restrict__ ad,
                                                     const float4* __restrict__ add,
                                                     const int* __restrict__ offs,
                                                     const int* __restrict__ csrc,
                                                     float* __restrict__ agg) {
    const int n = (blockIdx.x * 256 + threadIdx.x) >> 6;
    const int L = threadIdx.x & 63;
    if (n >= Nn) return;
    const int start = offs[n];
    const int deg = offs[n + 1] - start;
    float2* o2 = (float2*)(agg + (size_t)n * 384);
    if (deg == 0) {
        float2 z = make_float2(0.f, 0.f);
        o2[L] = z; o2[64 + L] = z; o2[128 + L] = z;
        return;
    }
    const float4 adn = add[n];
    // ---- pass 1: online softmax stats, all 3 heads ----
    float m0 = -1e30f, m1 = -1e30f, m2 = -1e30f;
    float s0 = 0.f, s1 = 0.f, s2 = 0.f;
    for (int i = L; i < deg; i += 64) {
        int sn = csrc[start + i];
        float4 a4 = ad[sn];
        float a0 = lrelu(a4.x + adn.x);
        float a1 = lrelu(a4.y + adn.y);
        float a2 = lrelu(a4.z + adn.z);
        float nm;
        nm = fmaxf(m0, a0); s0 = s0 * __expf(m0 - nm) + __expf(a0 - nm); m0 = nm;
        nm = fmaxf(m1, a1); s1 = s1 * __expf(m1 - nm) + __expf(a1 - nm); m1 = nm;
        nm = fmaxf(m2, a2); s2 = s2 * __expf(m2 - nm) + __expf(a2 - nm); m2 = nm;
    }
#pragma unroll
    for (int o = 32; o > 0; o >>= 1) {
        float om, os, nm;
        om = __shfl_xor(m0, o, 64); os = __shfl_xor(s0, o, 64);
        nm = fmaxf(m0, om); s0 = s0 * __expf(m0 - nm) + os * __expf(om - nm); m0 = nm;
        om = __shfl_xor(m1, o, 64); os = __shfl_xor(s1, o, 64);
        nm = fmaxf(m1, om); s1 = s1 * __expf(m1 - nm) + os * __expf(om - nm); m1 = nm;
        om = __shfl_xor(m2, o, 64); os = __shfl_xor(s2, o, 64);
        nm = fmaxf(m2, om); s2 = s2 * __expf(m2 - nm) + os * __expf(om - nm); m2 = nm;
    }
    const float i0 = 1.f / s0, i1 = 1.f / s1, i2 = 1.f / s2;
    // ---- pass 2: gather + weighted sum ----
    float2 acc0 = make_float2(0.f, 0.f), acc1 = acc0, acc2 = acc0;
    for (int base = 0; base < deg; base += 64) {
        int cnt = deg - base; if (cnt > 64) cnt = 64;
        int sn = 0; float c0 = 0.f, c1 = 0.f, c2 = 0.f;
        if (L < cnt) {
            sn = csrc[start + base + L];
            float4 a4 = ad[sn];
            c0 = __expf(lrelu(a4.x + adn.x) - m0) * i0;
            c1 = __expf(lrelu(a4.y + adn.y) - m1) * i1;
            c2 = __expf(lrelu(a4.z + adn.z) - m2) * i2;
        }
        for (int j = 0; j < cnt; j++) {
            int    s_n = __shfl(sn, j, 64);
            float  w0  = __shfl(c0, j, 64);
            float  w1  = __shfl(c1, j, 64);
            float  w2  = __shfl(c2, j, 64);
            const float2* r2 = (const float2*)(wv + (size_t)s_n * 384);
            float2 v0 = r2[L], v1 = r2[64 + L], v2 = r2[128 + L];
            acc0.x += w0 * v0.x; acc0.y += w0 * v0.y;
            acc1.x += w1 * v1.x; acc1.y += w1 * v1.y;
            acc2.x += w2 * v2.x; acc2.y += w2 * v2.y;
        }
    }
    o2[L] = acc0; o2[64 + L] = acc1; o2[128 + L] = acc2;
}

// ---------------------------------------------------------------------------
// LN epilogue: x = hcur + (deg>0 ? res : 0); LayerNorm; ReLU; readout accumulate
// ---------------------------------------------------------------------------
__global__ void ln_epilogue(const float* __restrict__ res, const int* __restrict__ deg,
                            const float* __restrict__ gamma, const float* __restrict__ beta,
                            const int* __restrict__ gid, float* __restrict__ hcur,
                            float* __restrict__ reado) {
    int n = blockIdx.x, tid = threadIdx.x;
    __shared__ float red[128];
    float x = hcur[(size_t)n * Hh + tid];
    if (deg[n] > 0) x += res[(size_t)n * Hh + tid];
    red[tid] = x; __syncthreads();
    for (int o = 64; o > 0; o >>= 1) { if (tid < o) red[tid] += red[tid + o]; __syncthreads(); }
    float mu = red[0] * (1.f / 128.f); __syncthreads();
    float d = x - mu;
    red[tid] = d * d; __syncthreads();
    for (int o = 64; o > 0; o >>= 1) { if (tid < o) red[tid] += red[tid + o]; __syncthreads(); }
    float var = red[0] * (1.f / 128.f);
    float y = d * rsqrtf(var + EPS) * gamma[tid] + beta[tid];
    y = fmaxf(y, 0.f);
    hcur[(size_t)n * Hh + tid] = y;
    atomicAdd(&reado[(size_t)gid[n] * Hh + tid], y);
}

// ---------------------------------------------------------------------------
// GRU layer 0: input [B,3,128], bidirectional, hidden 128.
// ---------------------------------------------------------------------------
__global__ __launch_bounds__(128) void gru_layer0(const float* __restrict__ reado,
                                                  const int* __restrict__ gcnt,
                                                  const float* __restrict__ Wih,
                                                  const float* __restrict__ Whh,
                                                  const float* __restrict__ bih,
                                                  const float* __restrict__ bhh,
                                                  float* __restrict__ y0,
                                                  float* __restrict__ fin) {
    const int b = blockIdx.x, tid = threadIdx.x;
    __shared__ float xb[3][128];
    __shared__ float hs[128];
    float invc = 1.f / fmaxf((float)gcnt[b], 1.f);
    for (int t = 0; t < 3; t++)
        xb[t][tid] = reado[(size_t)t * Bb * Hh + (size_t)b * Hh + tid] * invc;
    for (int dir = 0; dir < 2; dir++) {
        const float* Wi = Wih + (size_t)dir * 384 * 128;
        const float* Wh = Whh + (size_t)dir * 384 * 128;
        const float* bi = bih + dir * 384;
        const float* bh = bhh + dir * 384;
        __syncthreads();
        hs[tid] = 0.f;
        float hreg = 0.f;
        __syncthreads();
        for (int step = 0; step < 3; step++) {
            int t = dir ? 2 - step : step;
            float gir = bi[tid], giz = bi[tid + 128], gin = bi[tid + 256];
            float ghr = bh[tid], ghz = bh[tid + 128], ghn = bh[tid + 256];
            const float* wir = Wi + (size_t)tid * 128;
            const float* wiz = Wi + (size_t)(tid + 128) * 128;
            const float* win = Wi + (size_t)(tid + 256) * 128;
            const float* whr = Wh + (size_t)tid * 128;
            const float* whz = Wh + (size_t)(tid + 128) * 128;
            const float* whn = Wh + (size_t)(tid + 256) * 128;
            for (int k = 0; k < 128; k++) {
                float xv = xb[t][k], hv = hs[k];
                gir += wir[k] * xv; giz += wiz[k] * xv; gin += win[k] * xv;
                ghr += whr[k] * hv; ghz += whz[k] * hv; ghn += whn[k] * hv;
            }
            float r = 1.f / (1.f + __expf(-(gir + ghr)));
            float z = 1.f / (1.f + __expf(-(giz + ghz)));
            float nn2 = tanhf(gin + r * ghn);
            hreg = (1.f - z) * nn2 + z * hreg;
            __syncthreads();
            hs[tid] = hreg;
            y0[(size_t)b * 768 + t * 256 + dir * 128 + tid] = hreg;
            __syncthreads();
        }
        fin[(size_t)dir * Bb * Hh + (size_t)b * Hh + tid] = hreg;
    }
}

// GRU layer 1: input [B,3,256], bidirectional, hidden 128.
__global__ __launch_bounds__(128) void gru_layer1(const float* __restrict__ y0,
                                                  const float* __restrict__ Wih,
                                                  const float* __restrict__ Whh,
                                                  const float* __restrict__ bih,
                                                  const float* __restrict__ bhh,
                                                  float* __restrict__ fin) {
    const int b = blockIdx.x, tid = threadIdx.x;
    __shared__ float xb[3][256];
    __shared__ float hs[128];
    for (int t = 0; t < 3; t++) {
        xb[t][tid]       = y0[(size_t)b * 768 + t * 256 + tid];
        xb[t][tid + 128] = y0[(size_t)b * 768 + t * 256 + 128 + tid];
    }
    for (int dir = 0; dir < 2; dir++) {
        const float* Wi = Wih + (size_t)dir * 384 * 256;
        const float* Wh = Whh + (size_t)dir * 384 * 128;
        const float* bi = bih + dir * 384;
        const float* bh = bhh + dir * 384;
        __syncthreads();
        hs[tid] = 0.f;
        float hreg = 0.f;
        __syncthreads();
        for (int step = 0; step < 3; step++) {
            int t = dir ? 2 - step : step;
            float gir = bi[tid], giz = bi[tid + 128], gin = bi[tid + 256];
            float ghr = bh[tid], ghz = bh[tid + 128], ghn = bh[tid + 256];
            const float* wir = Wi + (size_t)tid * 256;
            const float* wiz = Wi + (size_t)(tid + 128) * 256;
            const float* win = Wi + (size_t)(tid + 256) * 256;
            const float* whr = Wh + (size_t)tid * 128;
            const float* whz = Wh + (size_t)(tid + 128) * 128;
            const float* whn = Wh + (size_t)(tid + 256) * 128;
            for (int k = 0; k < 256; k++) {
                float xv = xb[t][k];
                gir += wir[k] * xv; giz += wiz[k] * xv; gin += win[k] * xv;
            }
            for (int k = 0; k < 128; k++) {
                float hv = hs[k];
                ghr += whr[k] * hv; ghz += whz[k] * hv; ghn += whn[k] * hv;
            }
            float r = 1.f / (1.f + __expf(-(gir + ghr)));
            float z = 1.f / (1.f + __expf(-(giz + ghz)));
            float nn2 = tanhf(gin + r * ghn);
            hreg = (1.f - z) * nn2 + z * hreg;
            __syncthreads();
            hs[tid] = hreg;
            __syncthreads();
        }
        fin[(size_t)(2 + dir) * Bb * Hh + (size_t)b * Hh + tid] = hreg;
    }
}

__global__ void final_mean(const float* __restrict__ fin, float* __restrict__ out) {
    int b = blockIdx.x, tid = threadIdx.x;
    const size_t s = (size_t)Bb * Hh;
    out[(size_t)b * Hh + tid] = 0.25f * (fin[b * Hh + tid] + fin[s + b * Hh + tid] +
                                         fin[2 * s + b * Hh + tid] + fin[3 * s + b * Hh + tid]);
}

// ---------------------------------------------------------------------------
extern "C" void kernel_launch(void* const* d_in, const int* in_sizes, int n_in,
                              void* d_out, int out_size, void* d_ws, size_t ws_size,
                              hipStream_t stream) {
    const float* h      = (const float*)d_in[0];
    const int*   wid    = (const int*)d_in[1];
    const int*   src    = (const int*)d_in[2];
    const int*   dst    = (const int*)d_in[3];
    const int*   gid    = (const int*)d_in[4];
    const float* projW  = (const float*)d_in[5];
    const float* projB  = (const float*)d_in[6];
    const float* convWn = (const float*)d_in[7];
    const float* convBn = (const float*)d_in[8];
    const float* convAtt= (const float*)d_in[9];
    const float* convWs = (const float*)d_in[10];
    const float* convB  = (const float*)d_in[11];
    const float* convG  = (const float*)d_in[12];
    const float* convBe = (const float*)d_in[13];
    const float* Wih0   = (const float*)d_in[14];
    const float* Whh0   = (const float*)d_in[15];
    const float* bih0   = (const float*)d_in[16];
    const float* bhh0   = (const float*)d_in[17];
    const float* Wih1   = (const float*)d_in[18];
    const float* Whh1   = (const float*)d_in[19];
    const float* bih1   = (const float*)d_in[20];
    const float* bhh1   = (const float*)d_in[21];
    float* out = (float*)d_out;

    char* p = (char*)d_ws;
    auto alloc_f = [&](size_t n) { float* r = (float*)p; p += n * sizeof(float); return r; };
    auto alloc_i = [&](size_t n) { int* r = (int*)p; p += n * sizeof(int); return r; };
    auto alloc_s = [&](size_t n) { unsigned short* r = (unsigned short*)p; p += n * sizeof(unsigned short); return r; };
    float* hcur  = alloc_f((size_t)Nn * Hh);
    float* wv    = alloc_f((size_t)Nn * 384);
    float* agg   = alloc_f((size_t)Nn * 384);
    float* res   = alloc_f((size_t)Nn * Hh);
    float* adbuf = alloc_f((size_t)Nn * 4);
    float* addbuf= alloc_f((size_t)Nn * 4);
    float* reado = alloc_f((size_t)3 * Bb * Hh);
    float* y0    = alloc_f((size_t)Bb * 3 * 256);
    float* fin   = alloc_f((size_t)4 * Bb * Hh);
    int* deg  = alloc_i(Nn);
    int* offs = alloc_i(Nn + 1);
    int* cur  = alloc_i(Nn);
    int* csrc = alloc_i(Ee);
    int* gcnt = alloc_i(Bb);
    unsigned short* pBth  = alloc_s(128 * 128);
    unsigned short* pBtl  = alloc_s(128 * 128);
    unsigned short* WnTh[2] = { alloc_s(384 * 128), alloc_s(384 * 128) };
    unsigned short* WnTl[2] = { alloc_s(384 * 128), alloc_s(384 * 128) };
    unsigned short* WsTh[2] = { alloc_s(128 * 384), alloc_s(128 * 384) };
    unsigned short* WsTl[2] = { alloc_s(128 * 384), alloc_s(128 * 384) };

    hipMemsetAsync(reado, 0, (size_t)3 * Bb * Hh * sizeof(float), stream);
    hipMemsetAsync(deg, 0, Nn * sizeof(int), stream);
    hipMemsetAsync(gcnt, 0, Bb * sizeof(int), stream);

    hist_dst<<<1250, 256, 0, stream>>>(dst, deg);
    scan_offsets<<<1, 1024, 0, stream>>>(deg, offs, cur);
    fill_csr<<<1250, 256, 0, stream>>>(dst, src, cur, csrc);

    wprep<<<(128 * 128 + 255) / 256, 256, 0, stream>>>(projW + (size_t)Vv * Hh, 128, 128, pBth, pBtl);
    for (int l = 0; l < 2; l++) {
        wprep<<<(128 * 384 + 255) / 256, 256, 0, stream>>>(convWn + (size_t)l * 128 * 384, 128, 384, WnTh[l], WnTl[l]);
        wprep<<<(384 * 128 + 255) / 256, 256, 0, stream>>>(convWs + (size_t)l * 384 * 128, 384, 128, WsTh[l], WsTl[l]);
    }

    gemm_mfma<<<dim3(1, (Nn + 127) / 128), 256, 0, stream>>>(h, pBth, pBtl, nullptr, res, Nn, 128, 128);
    proj_epilogue<<<Nn, 128, 0, stream>>>(res, projW, projB, wid, gid, hcur, reado, gcnt);

    const int nwaveblocks = (Nn * 64 + 255) / 256;   // 5000
    for (int l = 0; l < 2; l++) {
        gemm_mfma<<<dim3(3, (Nn + 127) / 128), 256, 0, stream>>>(
            hcur, WnTh[l], WnTl[l], convBn + l * 384, wv, Nn, 384, 128);
        att_dots<<<nwaveblocks, 256, 0, stream>>>(wv, convAtt + (size_t)l * 3 * 256,
                                                  (float4*)adbuf, (float4*)addbuf);
        gat_aggregate<<<nwaveblocks, 256, 0, stream>>>(wv, (const float4*)adbuf, (const float4*)addbuf,
                                                       offs, csrc, agg);
        gemm_mfma<<<dim3(1, (Nn + 127) / 128), 256, 0, stream>>>(
            agg, WsTh[l], WsTl[l], convB + l * Hh, res, Nn, 128, 384);
        ln_epilogue<<<Nn, 128, 0, stream>>>(res, deg, convG + l * Hh, convBe + l * Hh,
                                            gid, hcur, reado + (size_t)(l + 1) * Bb * Hh);
    }

    gru_layer0<<<Bb, 128, 0, stream>>>(reado, gcnt, Wih0, Whh0, bih0, bhh0, y0, fin);
    gru_layer1<<<Bb, 128, 0, stream>>>(y0, Wih1, Whh1, bih1, bhh1, fin);
    final_mean<<<Bb, 128, 0, stream>>>(fin, out);
}

// Round 4
// 656.326 us; speedup vs baseline: 1.6353x; 1.2721x over previous
//
#include <hip/hip_runtime.h>
#include <cstddef>

// Problem constants (from reference)
static constexpr int Nn    = 20000;
static constexpr int Ee    = 320000;
static constexpr int Vv    = 100;
static constexpr int Hh    = 128;
static constexpr int HEADS = 3;
static constexpr int Bb    = 200;
static constexpr float NEG = 0.2f;
static constexpr float EPS = 1e-5f;

typedef short bf16x8 __attribute__((ext_vector_type(8)));
typedef float f32x4  __attribute__((ext_vector_type(4)));

__device__ inline unsigned short bf16_rne(float x) {
    unsigned u = __builtin_bit_cast(unsigned, x);
    u += 0x7FFFu + ((u >> 16) & 1u);
    return (unsigned short)(u >> 16);
}
__device__ inline float bf16_f(unsigned short h) {
    unsigned u = ((unsigned)h) << 16;
    return __builtin_bit_cast(float, u);
}
__device__ inline float lrelu(float a) { return a >= 0.f ? a : NEG * a; }
__device__ inline float sigmoidf(float x) { return 1.f / (1.f + __expf(-x)); }

// ---------------------------------------------------------------------------
// CSR build: histogram over dst, single-block scan, fill (stores src ids)
// ---------------------------------------------------------------------------
__global__ void hist_dst(const int* __restrict__ dst, int* __restrict__ deg) {
    for (int i = blockIdx.x * blockDim.x + threadIdx.x; i < Ee; i += gridDim.x * blockDim.x)
        atomicAdd(&deg[dst[i]], 1);
}

__global__ __launch_bounds__(1024) void scan_offsets(const int* __restrict__ deg,
                                                     int* __restrict__ offs,
                                                     int* __restrict__ cur) {
    __shared__ int sums[1024];
    const int tid = threadIdx.x;
    const int per = (Nn + 1023) >> 10;          // 20
    int begin = tid * per;
    int end = begin + per; if (end > Nn) end = Nn;
    if (begin > Nn) begin = Nn;
    int s = 0;
    for (int i = begin; i < end; i++) s += deg[i];
    sums[tid] = s;
    __syncthreads();
    for (int off = 1; off < 1024; off <<= 1) {
        int v = (tid >= off) ? sums[tid - off] : 0;
        __syncthreads();
        sums[tid] += v;
        __syncthreads();
    }
    int run = sums[tid] - s;                    // exclusive prefix
    for (int i = begin; i < end; i++) {
        offs[i] = run; cur[i] = run;
        run += deg[i];
    }
    if (end == Nn) offs[Nn] = run;
}

__global__ void fill_csr(const int* __restrict__ dst, const int* __restrict__ src,
                         int* __restrict__ cur, int* __restrict__ csrc) {
    for (int i = blockIdx.x * blockDim.x + threadIdx.x; i < Ee; i += gridDim.x * blockDim.x) {
        int p = atomicAdd(&cur[dst[i]], 1);
        csrc[p] = src[i];
    }
}

// ---------------------------------------------------------------------------
// Weight prep: B[K][N] fp32 -> Bt_hi/Bt_lo [N][K] bf16 (split hi+lo)
// ---------------------------------------------------------------------------
__global__ void wprep(const float* __restrict__ B, int K, int N,
                      unsigned short* __restrict__ Bth, unsigned short* __restrict__ Btl) {
    int idx = blockIdx.x * blockDim.x + threadIdx.x;
    if (idx >= K * N) return;
    int k = idx / N, n = idx % N;
    float v = B[idx];
    unsigned short h = bf16_rne(v);
    unsigned short l = bf16_rne(v - bf16_f(h));
    Bth[(size_t)n * K + k] = h;
    Btl[(size_t)n * K + k] = l;
}

// GRU weight transpose: W[2][384][K] -> WT[2][K][384]
__global__ void gru_wprep(const float* __restrict__ W, int K, float* __restrict__ WT) {
    int idx = blockIdx.x * blockDim.x + threadIdx.x;
    int total = 2 * 384 * K;
    if (idx >= total) return;
    int d = idx / (384 * K);
    int r = idx - d * 384 * K;
    int j = r / K, k = r - j * K;
    WT[(size_t)d * K * 384 + (size_t)k * 384 + j] = W[idx];
}

// ---------------------------------------------------------------------------
// Split-bf16 MFMA GEMM: C[M,N] = A[M,K](fp32) @ B + bias
// B supplied transposed hi/lo bf16: Bt[N][K].
// C ~= Ahi*Bhi + Ahi*Blo + Alo*Bhi  (fp32 accumulate)
// BM=128, BN=128, BK=32; 256 threads = 4 waves (2x2); wave tile 64x64 (4x4 MFMA).
// ---------------------------------------------------------------------------
__global__ __launch_bounds__(256) void gemm_mfma(const float* __restrict__ A,
                                                 const unsigned short* __restrict__ Bth,
                                                 const unsigned short* __restrict__ Btl,
                                                 const float* __restrict__ bias,
                                                 float* __restrict__ C,
                                                 int M, int N, int K) {
    __shared__ unsigned short As_hi[128][40];   // [m][k]
    __shared__ unsigned short As_lo[128][40];
    __shared__ unsigned short Bs_hi[128][40];   // [n][k]
    __shared__ unsigned short Bs_lo[128][40];
    const int tid  = threadIdx.x;
    const int row0 = blockIdx.y * 128;
    const int col0 = blockIdx.x * 128;
    const int w    = tid >> 6;       // wave 0..3
    const int wm   = w >> 1;         // 0..1 (M)
    const int wn   = w & 1;          // 0..1 (N)
    const int L    = tid & 63;
    const int lrow = L & 15;
    const int lq   = L >> 4;         // 0..3

    f32x4 acc[4][4];
#pragma unroll
    for (int i = 0; i < 4; i++)
#pragma unroll
        for (int j = 0; j < 4; j++) acc[i][j] = (f32x4){0.f, 0.f, 0.f, 0.f};

    for (int kb = 0; kb < K; kb += 32) {
        // ---- stage A (fp32 -> hi/lo bf16), 128 x 32 ----
#pragma unroll
        for (int it = 0; it < 4; it++) {
            int idx = tid + it * 256;          // 0..1023
            int m  = idx >> 3;                 // 0..127
            int kq = (idx & 7) * 4;            // 0,4,...,28
            int gr = row0 + m;
            float4 v = make_float4(0.f, 0.f, 0.f, 0.f);
            if (gr < M) v = *(const float4*)(A + (size_t)gr * K + kb + kq);
            unsigned short h0 = bf16_rne(v.x), h1 = bf16_rne(v.y),
                           h2 = bf16_rne(v.z), h3 = bf16_rne(v.w);
            short4 hi4 = make_short4((short)h0, (short)h1, (short)h2, (short)h3);
            short4 lo4 = make_short4((short)bf16_rne(v.x - bf16_f(h0)),
                                     (short)bf16_rne(v.y - bf16_f(h1)),
                                     (short)bf16_rne(v.z - bf16_f(h2)),
                                     (short)bf16_rne(v.w - bf16_f(h3)));
            *(short4*)&As_hi[m][kq] = hi4;
            *(short4*)&As_lo[m][kq] = lo4;
        }
        // ---- stage B^T (already bf16), 128 n x 32 k ----
        {
            int n  = tid >> 1;                 // 0..127
            int kh = (tid & 1) * 16;           // 0 or 16
            const unsigned short* sh = Bth + (size_t)(col0 + n) * K + kb + kh;
            const unsigned short* sl = Btl + (size_t)(col0 + n) * K + kb + kh;
            *(float4*)&Bs_hi[n][kh]     = *(const float4*)sh;
            *(float4*)&Bs_hi[n][kh + 8] = *(const float4*)(sh + 8);
            *(float4*)&Bs_lo[n][kh]     = *(const float4*)sl;
            *(float4*)&Bs_lo[n][kh + 8] = *(const float4*)(sl + 8);
        }
        __syncthreads();
        // ---- fragments + MFMA ----
        bf16x8 ah[4], al[4], bh[4], bl[4];
#pragma unroll
        for (int mi = 0; mi < 4; mi++) {
            int r = wm * 64 + mi * 16 + lrow;
            ah[mi] = *(const bf16x8*)&As_hi[r][lq * 8];
            al[mi] = *(const bf16x8*)&As_lo[r][lq * 8];
        }
#pragma unroll
        for (int ni = 0; ni < 4; ni++) {
            int r = wn * 64 + ni * 16 + lrow;
            bh[ni] = *(const bf16x8*)&Bs_hi[r][lq * 8];
            bl[ni] = *(const bf16x8*)&Bs_lo[r][lq * 8];
        }
#pragma unroll
        for (int mi = 0; mi < 4; mi++)
#pragma unroll
            for (int ni = 0; ni < 4; ni++) {
                acc[mi][ni] = __builtin_amdgcn_mfma_f32_16x16x32_bf16(ah[mi], bh[ni], acc[mi][ni], 0, 0, 0);
                acc[mi][ni] = __builtin_amdgcn_mfma_f32_16x16x32_bf16(ah[mi], bl[ni], acc[mi][ni], 0, 0, 0);
                acc[mi][ni] = __builtin_amdgcn_mfma_f32_16x16x32_bf16(al[mi], bh[ni], acc[mi][ni], 0, 0, 0);
            }
        __syncthreads();
    }
    // ---- epilogue: C/D layout col=lane&15, row=(lane>>4)*4+reg ----
#pragma unroll
    for (int mi = 0; mi < 4; mi++)
#pragma unroll
        for (int ni = 0; ni < 4; ni++) {
            int col = col0 + wn * 64 + ni * 16 + lrow;
            float bb = bias ? bias[col] : 0.f;
#pragma unroll
            for (int r = 0; r < 4; r++) {
                int row = row0 + wm * 64 + mi * 16 + lq * 4 + r;
                if (row < M) C[(size_t)row * N + col] = acc[mi][ni][r] + bb;
            }
        }
}

// ---------------------------------------------------------------------------
// proj epilogue: hcur = gemm_out + projW[wid] + projB; readout0 accumulate
// ---------------------------------------------------------------------------
__global__ void proj_epilogue(const float* __restrict__ res, const float* __restrict__ projW,
                              const float* __restrict__ projB, const int* __restrict__ wid,
                              const int* __restrict__ gid, float* __restrict__ hcur,
                              float* __restrict__ reado, int* __restrict__ gcnt) {
    int n = blockIdx.x, tid = threadIdx.x;
    float v = res[(size_t)n * Hh + tid] + projW[(size_t)wid[n] * Hh + tid] + projB[tid];
    hcur[(size_t)n * Hh + tid] = v;
    atomicAdd(&reado[(size_t)gid[n] * Hh + tid], v);
    if (tid == 0) atomicAdd(&gcnt[gid[n]], 1);
}

// ---------------------------------------------------------------------------
// att_dots, one wave per node
// ---------------------------------------------------------------------------
__global__ __launch_bounds__(256) void att_dots(const float* __restrict__ wv,
                                                const float* __restrict__ att,
                                                float4* __restrict__ ad,
                                                float4* __restrict__ add) {
    const int wid_g = (blockIdx.x * 256 + threadIdx.x) >> 6;
    const int L = threadIdx.x & 63;
    if (wid_g >= Nn) return;
    const float2* w2 = (const float2*)(wv + (size_t)wid_g * 384);
    float s[3], d[3];
#pragma unroll
    for (int hd = 0; hd < 3; hd++) {
        float2 w = w2[hd * 64 + L];
        float2 as = *(const float2*)(att + hd * 256 + 2 * L);
        float2 at = *(const float2*)(att + hd * 256 + 128 + 2 * L);
        s[hd] = w.x * as.x + w.y * as.y;
        d[hd] = w.x * at.x + w.y * at.y;
    }
#pragma unroll
    for (int o = 32; o > 0; o >>= 1) {
#pragma unroll
        for (int hd = 0; hd < 3; hd++) {
            s[hd] += __shfl_xor(s[hd], o, 64);
            d[hd] += __shfl_xor(d[hd], o, 64);
        }
    }
    if (L == 0) {
        ad[wid_g]  = make_float4(s[0], s[1], s[2], 0.f);
        add[wid_g] = make_float4(d[0], d[1], d[2], 0.f);
    }
}

// ---------------------------------------------------------------------------
// GAT softmax-attention aggregation, one wave per dst node, zero barriers.
// ---------------------------------------------------------------------------
__global__ __launch_bounds__(256) void gat_aggregate(const float* __restrict__ wv,
                                                     const float4* __restrict__ ad,
                                                     const float4* __restrict__ add,
                                                     const int* __restrict__ offs,
                                                     const int* __restrict__ csrc,
                                                     float* __restrict__ agg) {
    const int n = (blockIdx.x * 256 + threadIdx.x) >> 6;
    const int L = threadIdx.x & 63;
    if (n >= Nn) return;
    const int start = offs[n];
    const int deg = offs[n + 1] - start;
    float2* o2 = (float2*)(agg + (size_t)n * 384);
    if (deg == 0) {
        float2 z = make_float2(0.f, 0.f);
        o2[L] = z; o2[64 + L] = z; o2[128 + L] = z;
        return;
    }
    const float4 adn = add[n];
    // ---- pass 1: online softmax stats, all 3 heads ----
    float m0 = -1e30f, m1 = -1e30f, m2 = -1e30f;
    float s0 = 0.f, s1 = 0.f, s2 = 0.f;
    for (int i = L; i < deg; i += 64) {
        int sn = csrc[start + i];
        float4 a4 = ad[sn];
        float a0 = lrelu(a4.x + adn.x);
        float a1 = lrelu(a4.y + adn.y);
        float a2 = lrelu(a4.z + adn.z);
        float nm;
        nm = fmaxf(m0, a0); s0 = s0 * __expf(m0 - nm) + __expf(a0 - nm); m0 = nm;
        nm = fmaxf(m1, a1); s1 = s1 * __expf(m1 - nm) + __expf(a1 - nm); m1 = nm;
        nm = fmaxf(m2, a2); s2 = s2 * __expf(m2 - nm) + __expf(a2 - nm); m2 = nm;
    }
#pragma unroll
    for (int o = 32; o > 0; o >>= 1) {
        float om, os, nm;
        om = __shfl_xor(m0, o, 64); os = __shfl_xor(s0, o, 64);
        nm = fmaxf(m0, om); s0 = s0 * __expf(m0 - nm) + os * __expf(om - nm); m0 = nm;
        om = __shfl_xor(m1, o, 64); os = __shfl_xor(s1, o, 64);
        nm = fmaxf(m1, om); s1 = s1 * __expf(m1 - nm) + os * __expf(om - nm); m1 = nm;
        om = __shfl_xor(m2, o, 64); os = __shfl_xor(s2, o, 64);
        nm = fmaxf(m2, om); s2 = s2 * __expf(m2 - nm) + os * __expf(om - nm); m2 = nm;
    }
    const float i0 = 1.f / s0, i1 = 1.f / s1, i2 = 1.f / s2;
    // ---- pass 2: gather + weighted sum ----
    float2 acc0 = make_float2(0.f, 0.f), acc1 = acc0, acc2 = acc0;
    for (int base = 0; base < deg; base += 64) {
        int cnt = deg - base; if (cnt > 64) cnt = 64;
        int sn = 0; float c0 = 0.f, c1 = 0.f, c2 = 0.f;
        if (L < cnt) {
            sn = csrc[start + base + L];
            float4 a4 = ad[sn];
            c0 = __expf(lrelu(a4.x + adn.x) - m0) * i0;
            c1 = __expf(lrelu(a4.y + adn.y) - m1) * i1;
            c2 = __expf(lrelu(a4.z + adn.z) - m2) * i2;
        }
        for (int j = 0; j < cnt; j++) {
            int    s_n = __shfl(sn, j, 64);
            float  w0  = __shfl(c0, j, 64);
            float  w1  = __shfl(c1, j, 64);
            float  w2  = __shfl(c2, j, 64);
            const float2* r2 = (const float2*)(wv + (size_t)s_n * 384);
            float2 v0 = r2[L], v1 = r2[64 + L], v2 = r2[128 + L];
            acc0.x += w0 * v0.x; acc0.y += w0 * v0.y;
            acc1.x += w1 * v1.x; acc1.y += w1 * v1.y;
            acc2.x += w2 * v2.x; acc2.y += w2 * v2.y;
        }
    }
    o2[L] = acc0; o2[64 + L] = acc1; o2[128 + L] = acc2;
}

// ---------------------------------------------------------------------------
// LN epilogue
// ---------------------------------------------------------------------------
__global__ void ln_epilogue(const float* __restrict__ res, const int* __restrict__ deg,
                            const float* __restrict__ gamma, const float* __restrict__ beta,
                            const int* __restrict__ gid, float* __restrict__ hcur,
                            float* __restrict__ reado) {
    int n = blockIdx.x, tid = threadIdx.x;
    __shared__ float red[128];
    float x = hcur[(size_t)n * Hh + tid];
    if (deg[n] > 0) x += res[(size_t)n * Hh + tid];
    red[tid] = x; __syncthreads();
    for (int o = 64; o > 0; o >>= 1) { if (tid < o) red[tid] += red[tid + o]; __syncthreads(); }
    float mu = red[0] * (1.f / 128.f); __syncthreads();
    float d = x - mu;
    red[tid] = d * d; __syncthreads();
    for (int o = 64; o > 0; o >>= 1) { if (tid < o) red[tid] += red[tid + o]; __syncthreads(); }
    float var = red[0] * (1.f / 128.f);
    float y = d * rsqrtf(var + EPS) * gamma[tid] + beta[tid];
    y = fmaxf(y, 0.f);
    hcur[(size_t)n * Hh + tid] = y;
    atomicAdd(&reado[(size_t)gid[n] * Hh + tid], y);
}

// ---------------------------------------------------------------------------
// GRU layer 0: grid = 400 blocks (b*2+dir), 384 threads (one per gate-unit j).
// Transposed weights WT[dir][k][j] -> coalesced loads. gi precomputed for all
// 3 timesteps in one pass (weight loaded once, 3 FMAs).
// ---------------------------------------------------------------------------
__global__ __launch_bounds__(384) void gru_layer0(const float* __restrict__ reado,
                                                  const int* __restrict__ gcnt,
                                                  const float* __restrict__ WihT,
                                                  const float* __restrict__ WhhT,
                                                  const float* __restrict__ bih,
                                                  const float* __restrict__ bhh,
                                                  float* __restrict__ y0,
                                                  float* __restrict__ fin) {
    const int b = blockIdx.x >> 1, dir = blockIdx.x & 1;
    const int j = threadIdx.x;                  // 0..383
    __shared__ float xs[3][128];
    __shared__ float hs[128];
    __shared__ float gil[384], ghl[384];
    if (j < 128) {
        float invc = 1.f / fmaxf((float)gcnt[b], 1.f);
#pragma unroll
        for (int t = 0; t < 3; t++)
            xs[t][j] = reado[(size_t)t * Bb * Hh + (size_t)b * Hh + j] * invc;
        hs[j] = 0.f;
    }
    __syncthreads();
    const float* Wi = WihT + (size_t)dir * 128 * 384;
    const float* Wh = WhhT + (size_t)dir * 128 * 384;
    float gi[3];
    gi[0] = gi[1] = gi[2] = bih[dir * 384 + j];
    for (int k = 0; k < 128; k++) {
        float w = Wi[(size_t)k * 384 + j];
        gi[0] += w * xs[0][k]; gi[1] += w * xs[1][k]; gi[2] += w * xs[2][k];
    }
    const float bhj = bhh[dir * 384 + j];
    for (int step = 0; step < 3; step++) {
        int t = dir ? 2 - step : step;
        float g = bhj;
        for (int k = 0; k < 128; k++) g += Wh[(size_t)k * 384 + j] * hs[k];
        ghl[j] = g;
        gil[j] = gi[t];
        __syncthreads();
        if (j < 128) {
            float r = sigmoidf(gil[j] + ghl[j]);
            float z = sigmoidf(gil[j + 128] + ghl[j + 128]);
            float nn2 = tanhf(gil[j + 256] + r * ghl[j + 256]);
            float hnew = (1.f - z) * nn2 + z * hs[j];
            hs[j] = hnew;
            y0[(size_t)b * 768 + t * 256 + dir * 128 + j] = hnew;
            if (step == 2) fin[(size_t)dir * Bb * Hh + (size_t)b * Hh + j] = hnew;
        }
        __syncthreads();
    }
}

// GRU layer 1: input y0 [B][3][256]; same structure, K_ih = 256.
__global__ __launch_bounds__(384) void gru_layer1(const float* __restrict__ y0,
                                                  const float* __restrict__ WihT,
                                                  const float* __restrict__ WhhT,
                                                  const float* __restrict__ bih,
                                                  const float* __restrict__ bhh,
                                                  float* __restrict__ fin) {
    const int b = blockIdx.x >> 1, dir = blockIdx.x & 1;
    const int j = threadIdx.x;                  // 0..383
    __shared__ float xs[3][256];
    __shared__ float hs[128];
    __shared__ float gil[384], ghl[384];
    if (j < 256) {
#pragma unroll
        for (int t = 0; t < 3; t++)
            xs[t][j] = y0[(size_t)b * 768 + t * 256 + j];
    }
    if (j < 128) hs[j] = 0.f;
    __syncthreads();
    const float* Wi = WihT + (size_t)dir * 256 * 384;
    const float* Wh = WhhT + (size_t)dir * 128 * 384;
    float gi[3];
    gi[0] = gi[1] = gi[2] = bih[dir * 384 + j];
    for (int k = 0; k < 256; k++) {
        float w = Wi[(size_t)k * 384 + j];
        gi[0] += w * xs[0][k]; gi[1] += w * xs[1][k]; gi[2] += w * xs[2][k];
    }
    const float bhj = bhh[dir * 384 + j];
    for (int step = 0; step < 3; step++) {
        int t = dir ? 2 - step : step;
        float g = bhj;
        for (int k = 0; k < 128; k++) g += Wh[(size_t)k * 384 + j] * hs[k];
        ghl[j] = g;
        gil[j] = gi[t];
        __syncthreads();
        if (j < 128) {
            float r = sigmoidf(gil[j] + ghl[j]);
            float z = sigmoidf(gil[j + 128] + ghl[j + 128]);
            float nn2 = tanhf(gil[j + 256] + r * ghl[j + 256]);
            float hnew = (1.f - z) * nn2 + z * hs[j];
            hs[j] = hnew;
            if (step == 2) fin[(size_t)(2 + dir) * Bb * Hh + (size_t)b * Hh + j] = hnew;
        }
        __syncthreads();
    }
}

__global__ void final_mean(const float* __restrict__ fin, float* __restrict__ out) {
    int b = blockIdx.x, tid = threadIdx.x;
    const size_t s = (size_t)Bb * Hh;
    out[(size_t)b * Hh + tid] = 0.25f * (fin[b * Hh + tid] + fin[s + b * Hh + tid] +
                                         fin[2 * s + b * Hh + tid] + fin[3 * s + b * Hh + tid]);
}

// ---------------------------------------------------------------------------
extern "C" void kernel_launch(void* const* d_in, const int* in_sizes, int n_in,
                              void* d_out, int out_size, void* d_ws, size_t ws_size,
                              hipStream_t stream) {
    const float* h      = (const float*)d_in[0];
    const int*   wid    = (const int*)d_in[1];
    const int*   src    = (const int*)d_in[2];
    const int*   dst    = (const int*)d_in[3];
    const int*   gid    = (const int*)d_in[4];
    const float* projW  = (const float*)d_in[5];
    const float* projB  = (const float*)d_in[6];
    const float* convWn = (const float*)d_in[7];
    const float* convBn = (const float*)d_in[8];
    const float* convAtt= (const float*)d_in[9];
    const float* convWs = (const float*)d_in[10];
    const float* convB  = (const float*)d_in[11];
    const float* convG  = (const float*)d_in[12];
    const float* convBe = (const float*)d_in[13];
    const float* Wih0   = (const float*)d_in[14];
    const float* Whh0   = (const float*)d_in[15];
    const float* bih0   = (const float*)d_in[16];
    const float* bhh0   = (const float*)d_in[17];
    const float* Wih1   = (const float*)d_in[18];
    const float* Whh1   = (const float*)d_in[19];
    const float* bih1   = (const float*)d_in[20];
    const float* bhh1   = (const float*)d_in[21];
    float* out = (float*)d_out;

    char* p = (char*)d_ws;
    auto alloc_f = [&](size_t n) { float* r = (float*)p; p += n * sizeof(float); return r; };
    auto alloc_i = [&](size_t n) { int* r = (int*)p; p += n * sizeof(int); return r; };
    auto alloc_s = [&](size_t n) { unsigned short* r = (unsigned short*)p; p += n * sizeof(unsigned short); return r; };
    float* hcur  = alloc_f((size_t)Nn * Hh);
    float* wv    = alloc_f((size_t)Nn * 384);
    float* agg   = alloc_f((size_t)Nn * 384);
    float* res   = alloc_f((size_t)Nn * Hh);
    float* adbuf = alloc_f((size_t)Nn * 4);
    float* addbuf= alloc_f((size_t)Nn * 4);
    float* reado = alloc_f((size_t)3 * Bb * Hh);
    float* y0    = alloc_f((size_t)Bb * 3 * 256);
    float* fin   = alloc_f((size_t)4 * Bb * Hh);
    // transposed GRU weights
    float* WihT0 = alloc_f((size_t)2 * 128 * 384);
    float* WhhT0 = alloc_f((size_t)2 * 128 * 384);
    float* WihT1 = alloc_f((size_t)2 * 256 * 384);
    float* WhhT1 = alloc_f((size_t)2 * 128 * 384);
    int* deg  = alloc_i(Nn);
    int* offs = alloc_i(Nn + 1);
    int* cur  = alloc_i(Nn);
    int* csrc = alloc_i(Ee);
    int* gcnt = alloc_i(Bb);
    unsigned short* pBth  = alloc_s(128 * 128);
    unsigned short* pBtl  = alloc_s(128 * 128);
    unsigned short* WnTh[2] = { alloc_s(384 * 128), alloc_s(384 * 128) };
    unsigned short* WnTl[2] = { alloc_s(384 * 128), alloc_s(384 * 128) };
    unsigned short* WsTh[2] = { alloc_s(128 * 384), alloc_s(128 * 384) };
    unsigned short* WsTl[2] = { alloc_s(128 * 384), alloc_s(128 * 384) };

    hipMemsetAsync(reado, 0, (size_t)3 * Bb * Hh * sizeof(float), stream);
    hipMemsetAsync(deg, 0, Nn * sizeof(int), stream);
    hipMemsetAsync(gcnt, 0, Bb * sizeof(int), stream);

    hist_dst<<<1250, 256, 0, stream>>>(dst, deg);
    scan_offsets<<<1, 1024, 0, stream>>>(deg, offs, cur);
    fill_csr<<<1250, 256, 0, stream>>>(dst, src, cur, csrc);

    wprep<<<(128 * 128 + 255) / 256, 256, 0, stream>>>(projW + (size_t)Vv * Hh, 128, 128, pBth, pBtl);
    for (int l = 0; l < 2; l++) {
        wprep<<<(128 * 384 + 255) / 256, 256, 0, stream>>>(convWn + (size_t)l * 128 * 384, 128, 384, WnTh[l], WnTl[l]);
        wprep<<<(384 * 128 + 255) / 256, 256, 0, stream>>>(convWs + (size_t)l * 384 * 128, 384, 128, WsTh[l], WsTl[l]);
    }
    gru_wprep<<<(2 * 384 * 128 + 255) / 256, 256, 0, stream>>>(Wih0, 128, WihT0);
    gru_wprep<<<(2 * 384 * 128 + 255) / 256, 256, 0, stream>>>(Whh0, 128, WhhT0);
    gru_wprep<<<(2 * 384 * 256 + 255) / 256, 256, 0, stream>>>(Wih1, 256, WihT1);
    gru_wprep<<<(2 * 384 * 128 + 255) / 256, 256, 0, stream>>>(Whh1, 128, WhhT1);

    gemm_mfma<<<dim3(1, (Nn + 127) / 128), 256, 0, stream>>>(h, pBth, pBtl, nullptr, res, Nn, 128, 128);
    proj_epilogue<<<Nn, 128, 0, stream>>>(res, projW, projB, wid, gid, hcur, reado, gcnt);

    const int nwaveblocks = (Nn * 64 + 255) / 256;   // 5000
    for (int l = 0; l < 2; l++) {
        gemm_mfma<<<dim3(3, (Nn + 127) / 128), 256, 0, stream>>>(
            hcur, WnTh[l], WnTl[l], convBn + l * 384, wv, Nn, 384, 128);
        att_dots<<<nwaveblocks, 256, 0, stream>>>(wv, convAtt + (size_t)l * 3 * 256,
                                                  (float4*)adbuf, (float4*)addbuf);
        gat_aggregate<<<nwaveblocks, 256, 0, stream>>>(wv, (const float4*)adbuf, (const float4*)addbuf,
                                                       offs, csrc, agg);
        gemm_mfma<<<dim3(1, (Nn + 127) / 128), 256, 0, stream>>>(
            agg, WsTh[l], WsTl[l], convB + l * Hh, res, Nn, 128, 384);
        ln_epilogue<<<Nn, 128, 0, stream>>>(res, deg, convG + l * Hh, convBe + l * Hh,
                                            gid, hcur, reado + (size_t)(l + 1) * Bb * Hh);
    }

    gru_layer0<<<2 * Bb, 384, 0, stream>>>(reado, gcnt, WihT0, WhhT0, bih0, bhh0, y0, fin);
    gru_layer1<<<2 * Bb, 384, 0, stream>>>(y0, WihT1, WhhT1, bih1, bhh1, fin);
    final_mean<<<Bb, 128, 0, stream>>>(fin, out);
}

// Round 5
// 582.694 us; speedup vs baseline: 1.8420x; 1.1264x over previous
//
#include <hip/hip_runtime.h>
#include <cstddef>

// Problem constants (from reference)
static constexpr int Nn    = 20000;
static constexpr int Ee    = 320000;
static constexpr int Vv    = 100;
static constexpr int Hh    = 128;
static constexpr int HEADS = 3;
static constexpr int Bb    = 200;
static constexpr float NEG = 0.2f;
static constexpr float EPS = 1e-5f;

typedef short bf16x8 __attribute__((ext_vector_type(8)));
typedef float f32x4  __attribute__((ext_vector_type(4)));

__device__ inline unsigned short bf16_rne(float x) {
    unsigned u = __builtin_bit_cast(unsigned, x);
    u += 0x7FFFu + ((u >> 16) & 1u);
    return (unsigned short)(u >> 16);
}
__device__ inline float bf16_f(unsigned short h) {
    unsigned u = ((unsigned)h) << 16;
    return __builtin_bit_cast(float, u);
}
__device__ inline float bf_lo(unsigned u) { return __builtin_bit_cast(float, u << 16); }
__device__ inline float bf_hi(unsigned u) { return __builtin_bit_cast(float, u & 0xFFFF0000u); }
__device__ inline float lrelu(float a) { return a >= 0.f ? a : NEG * a; }
__device__ inline float sigmoidf(float x) { return 1.f / (1.f + __expf(-x)); }

// ---------------------------------------------------------------------------
// CSR build: histogram over dst, single-block scan, fill (stores src ids)
// ---------------------------------------------------------------------------
__global__ void hist_dst(const int* __restrict__ dst, int* __restrict__ deg) {
    for (int i = blockIdx.x * blockDim.x + threadIdx.x; i < Ee; i += gridDim.x * blockDim.x)
        atomicAdd(&deg[dst[i]], 1);
}

__global__ __launch_bounds__(1024) void scan_offsets(const int* __restrict__ deg,
                                                     int* __restrict__ offs,
                                                     int* __restrict__ cur) {
    __shared__ int sums[1024];
    const int tid = threadIdx.x;
    const int per = (Nn + 1023) >> 10;          // 20
    int begin = tid * per;
    int end = begin + per; if (end > Nn) end = Nn;
    if (begin > Nn) begin = Nn;
    int s = 0;
    for (int i = begin; i < end; i++) s += deg[i];
    sums[tid] = s;
    __syncthreads();
    for (int off = 1; off < 1024; off <<= 1) {
        int v = (tid >= off) ? sums[tid - off] : 0;
        __syncthreads();
        sums[tid] += v;
        __syncthreads();
    }
    int run = sums[tid] - s;                    // exclusive prefix
    for (int i = begin; i < end; i++) {
        offs[i] = run; cur[i] = run;
        run += deg[i];
    }
    if (end == Nn) offs[Nn] = run;
}

__global__ void fill_csr(const int* __restrict__ dst, const int* __restrict__ src,
                         int* __restrict__ cur, int* __restrict__ csrc) {
    for (int i = blockIdx.x * blockDim.x + threadIdx.x; i < Ee; i += gridDim.x * blockDim.x) {
        int p = atomicAdd(&cur[dst[i]], 1);
        csrc[p] = src[i];
    }
}

// ---------------------------------------------------------------------------
// Fused weight prep (one launch): split-transpose 5 GEMM weights + transpose
// 4 GRU weights.
// ---------------------------------------------------------------------------
struct PrepArgs {
    const float *projW, *convWn, *convWs, *Wih0, *Whh0, *Wih1, *Whh1;
    unsigned short *pBth, *pBtl;
    unsigned short *WnTh0, *WnTl0, *WnTh1, *WnTl1;
    unsigned short *WsTh0, *WsTl0, *WsTh1, *WsTl1;
    float *WihT0, *WhhT0, *WihT1, *WhhT1;
};

__device__ inline void wsplit(const float* B, int K, int N, int idx,
                              unsigned short* Bth, unsigned short* Btl) {
    int k = idx / N, n = idx - k * N;
    float v = B[idx];
    unsigned short h = bf16_rne(v);
    unsigned short l = bf16_rne(v - bf16_f(h));
    Bth[(size_t)n * K + k] = h;
    Btl[(size_t)n * K + k] = l;
}
__device__ inline void gruT(const float* W, int K, int idx, float* WT) {
    int d = idx / (384 * K);
    int r = idx - d * 384 * K;
    int j = r / K, k = r - j * K;
    WT[(size_t)d * K * 384 + (size_t)k * 384 + j] = W[idx];
}

__global__ void prep_all(PrepArgs a) {
    int i = blockIdx.x * blockDim.x + threadIdx.x;
    if (i < 16384)  { wsplit(a.projW, 128, 128, i, a.pBth, a.pBtl); return; }   i -= 16384;
    if (i < 49152)  { wsplit(a.convWn, 128, 384, i, a.WnTh0, a.WnTl0); return; } i -= 49152;
    if (i < 49152)  { wsplit(a.convWn + 49152, 128, 384, i, a.WnTh1, a.WnTl1); return; } i -= 49152;
    if (i < 49152)  { wsplit(a.convWs, 384, 128, i, a.WsTh0, a.WsTl0); return; } i -= 49152;
    if (i < 49152)  { wsplit(a.convWs + 49152, 384, 128, i, a.WsTh1, a.WsTl1); return; } i -= 49152;
    if (i < 98304)  { gruT(a.Wih0, 128, i, a.WihT0); return; }  i -= 98304;
    if (i < 98304)  { gruT(a.Whh0, 128, i, a.WhhT0); return; }  i -= 98304;
    if (i < 196608) { gruT(a.Wih1, 256, i, a.WihT1); return; }  i -= 196608;
    if (i < 98304)  { gruT(a.Whh1, 128, i, a.WhhT1); }
}

// ---------------------------------------------------------------------------
// Split-bf16 MFMA GEMM core. BM=128, BN=128, BK=32; 256 threads (2x2 waves),
// wave tile 64x64 (4x4 MFMA 16x16x32). OUT_BF16 selects fp32 or bf16 C.
// ---------------------------------------------------------------------------
template <bool OUT_BF16>
__global__ __launch_bounds__(256) void gemm_mfma_t(const float* __restrict__ A,
                                                   const unsigned short* __restrict__ Bth,
                                                   const unsigned short* __restrict__ Btl,
                                                   const float* __restrict__ bias,
                                                   float* __restrict__ C,
                                                   unsigned short* __restrict__ Cb,
                                                   int M, int N, int K) {
    __shared__ unsigned short As_hi[128][40];
    __shared__ unsigned short As_lo[128][40];
    __shared__ unsigned short Bs_hi[128][40];
    __shared__ unsigned short Bs_lo[128][40];
    const int tid  = threadIdx.x;
    const int row0 = blockIdx.y * 128;
    const int col0 = blockIdx.x * 128;
    const int w    = tid >> 6;
    const int wm   = w >> 1;
    const int wn   = w & 1;
    const int L    = tid & 63;
    const int lrow = L & 15;
    const int lq   = L >> 4;

    f32x4 acc[4][4];
#pragma unroll
    for (int i = 0; i < 4; i++)
#pragma unroll
        for (int j = 0; j < 4; j++) acc[i][j] = (f32x4){0.f, 0.f, 0.f, 0.f};

    for (int kb = 0; kb < K; kb += 32) {
#pragma unroll
        for (int it = 0; it < 4; it++) {
            int idx = tid + it * 256;
            int m  = idx >> 3;
            int kq = (idx & 7) * 4;
            int gr = row0 + m;
            float4 v = make_float4(0.f, 0.f, 0.f, 0.f);
            if (gr < M) v = *(const float4*)(A + (size_t)gr * K + kb + kq);
            unsigned short h0 = bf16_rne(v.x), h1 = bf16_rne(v.y),
                           h2 = bf16_rne(v.z), h3 = bf16_rne(v.w);
            short4 hi4 = make_short4((short)h0, (short)h1, (short)h2, (short)h3);
            short4 lo4 = make_short4((short)bf16_rne(v.x - bf16_f(h0)),
                                     (short)bf16_rne(v.y - bf16_f(h1)),
                                     (short)bf16_rne(v.z - bf16_f(h2)),
                                     (short)bf16_rne(v.w - bf16_f(h3)));
            *(short4*)&As_hi[m][kq] = hi4;
            *(short4*)&As_lo[m][kq] = lo4;
        }
        {
            int n  = tid >> 1;
            int kh = (tid & 1) * 16;
            const unsigned short* sh = Bth + (size_t)(col0 + n) * K + kb + kh;
            const unsigned short* sl = Btl + (size_t)(col0 + n) * K + kb + kh;
            *(float4*)&Bs_hi[n][kh]     = *(const float4*)sh;
            *(float4*)&Bs_hi[n][kh + 8] = *(const float4*)(sh + 8);
            *(float4*)&Bs_lo[n][kh]     = *(const float4*)sl;
            *(float4*)&Bs_lo[n][kh + 8] = *(const float4*)(sl + 8);
        }
        __syncthreads();
        bf16x8 ah[4], al[4], bh[4], bl[4];
#pragma unroll
        for (int mi = 0; mi < 4; mi++) {
            int r = wm * 64 + mi * 16 + lrow;
            ah[mi] = *(const bf16x8*)&As_hi[r][lq * 8];
            al[mi] = *(const bf16x8*)&As_lo[r][lq * 8];
        }
#pragma unroll
        for (int ni = 0; ni < 4; ni++) {
            int r = wn * 64 + ni * 16 + lrow;
            bh[ni] = *(const bf16x8*)&Bs_hi[r][lq * 8];
            bl[ni] = *(const bf16x8*)&Bs_lo[r][lq * 8];
        }
#pragma unroll
        for (int mi = 0; mi < 4; mi++)
#pragma unroll
            for (int ni = 0; ni < 4; ni++) {
                acc[mi][ni] = __builtin_amdgcn_mfma_f32_16x16x32_bf16(ah[mi], bh[ni], acc[mi][ni], 0, 0, 0);
                acc[mi][ni] = __builtin_amdgcn_mfma_f32_16x16x32_bf16(ah[mi], bl[ni], acc[mi][ni], 0, 0, 0);
                acc[mi][ni] = __builtin_amdgcn_mfma_f32_16x16x32_bf16(al[mi], bh[ni], acc[mi][ni], 0, 0, 0);
            }
        __syncthreads();
    }
#pragma unroll
    for (int mi = 0; mi < 4; mi++)
#pragma unroll
        for (int ni = 0; ni < 4; ni++) {
            int col = col0 + wn * 64 + ni * 16 + lrow;
            float bb = bias ? bias[col] : 0.f;
#pragma unroll
            for (int r = 0; r < 4; r++) {
                int row = row0 + wm * 64 + mi * 16 + lq * 4 + r;
                if (row < M) {
                    float v = acc[mi][ni][r] + bb;
                    if (OUT_BF16) Cb[(size_t)row * N + col] = bf16_rne(v);
                    else          C[(size_t)row * N + col] = v;
                }
            }
        }
}

// ---------------------------------------------------------------------------
// proj epilogue: hcur = gemm_out + projW[wid] + projB; readout0 accumulate
// ---------------------------------------------------------------------------
__global__ void proj_epilogue(const float* __restrict__ res, const float* __restrict__ projW,
                              const float* __restrict__ projB, const int* __restrict__ wid,
                              const int* __restrict__ gid, float* __restrict__ hcur,
                              float* __restrict__ reado, int* __restrict__ gcnt) {
    int n = blockIdx.x, tid = threadIdx.x;
    float v = res[(size_t)n * Hh + tid] + projW[(size_t)wid[n] * Hh + tid] + projB[tid];
    hcur[(size_t)n * Hh + tid] = v;
    atomicAdd(&reado[(size_t)gid[n] * Hh + tid], v);
    if (tid == 0) atomicAdd(&gcnt[gid[n]], 1);
}

// ---------------------------------------------------------------------------
// att_dots, one wave per node, bf16 wv
// ---------------------------------------------------------------------------
__global__ __launch_bounds__(256) void att_dots(const unsigned short* __restrict__ wv,
                                                const float* __restrict__ att,
                                                float4* __restrict__ ad,
                                                float4* __restrict__ add) {
    const int wid_g = (blockIdx.x * 256 + threadIdx.x) >> 6;
    const int L = threadIdx.x & 63;
    if (wid_g >= Nn) return;
    const unsigned* wu = (const unsigned*)(wv + (size_t)wid_g * 384);
    float s[3], d[3];
#pragma unroll
    for (int hd = 0; hd < 3; hd++) {
        unsigned u = wu[hd * 64 + L];
        float w0 = bf_lo(u), w1 = bf_hi(u);
        float2 as = *(const float2*)(att + hd * 256 + 2 * L);
        float2 at = *(const float2*)(att + hd * 256 + 128 + 2 * L);
        s[hd] = w0 * as.x + w1 * as.y;
        d[hd] = w0 * at.x + w1 * at.y;
    }
#pragma unroll
    for (int o = 32; o > 0; o >>= 1) {
#pragma unroll
        for (int hd = 0; hd < 3; hd++) {
            s[hd] += __shfl_xor(s[hd], o, 64);
            d[hd] += __shfl_xor(d[hd], o, 64);
        }
    }
    if (L == 0) {
        ad[wid_g]  = make_float4(s[0], s[1], s[2], 0.f);
        add[wid_g] = make_float4(d[0], d[1], d[2], 0.f);
    }
}

// ---------------------------------------------------------------------------
// GAT softmax-attention aggregation, one wave per dst node, bf16 wv gather.
// ---------------------------------------------------------------------------
__global__ __launch_bounds__(256) void gat_aggregate(const unsigned short* __restrict__ wv,
                                                     const float4* __restrict__ ad,
                                                     const float4* __restrict__ add,
                                                     const int* __restrict__ offs,
                                                     const int* __restrict__ csrc,
                                                     float* __restrict__ agg) {
    const int n = (blockIdx.x * 256 + threadIdx.x) >> 6;
    const int L = threadIdx.x & 63;
    if (n >= Nn) return;
    const int start = offs[n];
    const int deg = offs[n + 1] - start;
    float2* o2 = (float2*)(agg + (size_t)n * 384);
    if (deg == 0) {
        float2 z = make_float2(0.f, 0.f);
        o2[L] = z; o2[64 + L] = z; o2[128 + L] = z;
        return;
    }
    const float4 adn = add[n];
    // ---- pass 1: online softmax stats, all 3 heads ----
    float m0 = -1e30f, m1 = -1e30f, m2 = -1e30f;
    float s0 = 0.f, s1 = 0.f, s2 = 0.f;
    for (int i = L; i < deg; i += 64) {
        int sn = csrc[start + i];
        float4 a4 = ad[sn];
        float a0 = lrelu(a4.x + adn.x);
        float a1 = lrelu(a4.y + adn.y);
        float a2 = lrelu(a4.z + adn.z);
        float nm;
        nm = fmaxf(m0, a0); s0 = s0 * __expf(m0 - nm) + __expf(a0 - nm); m0 = nm;
        nm = fmaxf(m1, a1); s1 = s1 * __expf(m1 - nm) + __expf(a1 - nm); m1 = nm;
        nm = fmaxf(m2, a2); s2 = s2 * __expf(m2 - nm) + __expf(a2 - nm); m2 = nm;
    }
#pragma unroll
    for (int o = 32; o > 0; o >>= 1) {
        float om, os, nm;
        om = __shfl_xor(m0, o, 64); os = __shfl_xor(s0, o, 64);
        nm = fmaxf(m0, om); s0 = s0 * __expf(m0 - nm) + os * __expf(om - nm); m0 = nm;
        om = __shfl_xor(m1, o, 64); os = __shfl_xor(s1, o, 64);
        nm = fmaxf(m1, om); s1 = s1 * __expf(m1 - nm) + os * __expf(om - nm); m1 = nm;
        om = __shfl_xor(m2, o, 64); os = __shfl_xor(s2, o, 64);
        nm = fmaxf(m2, om); s2 = s2 * __expf(m2 - nm) + os * __expf(om - nm); m2 = nm;
    }
    const float i0 = 1.f / s0, i1 = 1.f / s1, i2 = 1.f / s2;
    // ---- pass 2: gather + weighted sum (bf16 rows, 4B/lane/head) ----
    float2 acc0 = make_float2(0.f, 0.f), acc1 = acc0, acc2 = acc0;
    for (int base = 0; base < deg; base += 64) {
        int cnt = deg - base; if (cnt > 64) cnt = 64;
        int sn = 0; float c0 = 0.f, c1 = 0.f, c2 = 0.f;
        if (L < cnt) {
            sn = csrc[start + base + L];
            float4 a4 = ad[sn];
            c0 = __expf(lrelu(a4.x + adn.x) - m0) * i0;
            c1 = __expf(lrelu(a4.y + adn.y) - m1) * i1;
            c2 = __expf(lrelu(a4.z + adn.z) - m2) * i2;
        }
        for (int j = 0; j < cnt; j++) {
            int    s_n = __shfl(sn, j, 64);
            float  w0  = __shfl(c0, j, 64);
            float  w1  = __shfl(c1, j, 64);
            float  w2  = __shfl(c2, j, 64);
            const unsigned* r2 = (const unsigned*)(wv + (size_t)s_n * 384);
            unsigned u0 = r2[L], u1 = r2[64 + L], u2 = r2[128 + L];
            acc0.x += w0 * bf_lo(u0); acc0.y += w0 * bf_hi(u0);
            acc1.x += w1 * bf_lo(u1); acc1.y += w1 * bf_hi(u1);
            acc2.x += w2 * bf_lo(u2); acc2.y += w2 * bf_hi(u2);
        }
    }
    o2[L] = acc0; o2[64 + L] = acc1; o2[128 + L] = acc2;
}

// ---------------------------------------------------------------------------
// LN epilogue
// ---------------------------------------------------------------------------
__global__ void ln_epilogue(const float* __restrict__ res, const int* __restrict__ deg,
                            const float* __restrict__ gamma, const float* __restrict__ beta,
                            const int* __restrict__ gid, float* __restrict__ hcur,
                            float* __restrict__ reado) {
    int n = blockIdx.x, tid = threadIdx.x;
    __shared__ float red[128];
    float x = hcur[(size_t)n * Hh + tid];
    if (deg[n] > 0) x += res[(size_t)n * Hh + tid];
    red[tid] = x; __syncthreads();
    for (int o = 64; o > 0; o >>= 1) { if (tid < o) red[tid] += red[tid + o]; __syncthreads(); }
    float mu = red[0] * (1.f / 128.f); __syncthreads();
    float d = x - mu;
    red[tid] = d * d; __syncthreads();
    for (int o = 64; o > 0; o >>= 1) { if (tid < o) red[tid] += red[tid + o]; __syncthreads(); }
    float var = red[0] * (1.f / 128.f);
    float y = d * rsqrtf(var + EPS) * gamma[tid] + beta[tid];
    y = fmaxf(y, 0.f);
    hcur[(size_t)n * Hh + tid] = y;
    atomicAdd(&reado[(size_t)gid[n] * Hh + tid], y);
}

// ---------------------------------------------------------------------------
// GRU layer 0: grid = 400 blocks (b*2+dir), 384 threads (one per gate-unit j).
// ---------------------------------------------------------------------------
__global__ __launch_bounds__(384) void gru_layer0(const float* __restrict__ reado,
                                                  const int* __restrict__ gcnt,
                                                  const float* __restrict__ WihT,
                                                  const float* __restrict__ WhhT,
                                                  const float* __restrict__ bih,
                                                  const float* __restrict__ bhh,
                                                  float* __restrict__ y0,
                                                  float* __restrict__ fin) {
    const int b = blockIdx.x >> 1, dir = blockIdx.x & 1;
    const int j = threadIdx.x;
    __shared__ float xs[3][128];
    __shared__ float hs[128];
    __shared__ float gil[384], ghl[384];
    if (j < 128) {
        float invc = 1.f / fmaxf((float)gcnt[b], 1.f);
#pragma unroll
        for (int t = 0; t < 3; t++)
            xs[t][j] = reado[(size_t)t * Bb * Hh + (size_t)b * Hh + j] * invc;
        hs[j] = 0.f;
    }
    __syncthreads();
    const float* Wi = WihT + (size_t)dir * 128 * 384;
    const float* Wh = WhhT + (size_t)dir * 128 * 384;
    float gi[3];
    gi[0] = gi[1] = gi[2] = bih[dir * 384 + j];
    for (int k = 0; k < 128; k++) {
        float w = Wi[(size_t)k * 384 + j];
        gi[0] += w * xs[0][k]; gi[1] += w * xs[1][k]; gi[2] += w * xs[2][k];
    }
    const float bhj = bhh[dir * 384 + j];
    for (int step = 0; step < 3; step++) {
        int t = dir ? 2 - step : step;
        float g = bhj;
        for (int k = 0; k < 128; k++) g += Wh[(size_t)k * 384 + j] * hs[k];
        ghl[j] = g;
        gil[j] = gi[t];
        __syncthreads();
        if (j < 128) {
            float r = sigmoidf(gil[j] + ghl[j]);
            float z = sigmoidf(gil[j + 128] + ghl[j + 128]);
            float nn2 = tanhf(gil[j + 256] + r * ghl[j + 256]);
            float hnew = (1.f - z) * nn2 + z * hs[j];
            hs[j] = hnew;
            y0[(size_t)b * 768 + t * 256 + dir * 128 + j] = hnew;
            if (step == 2) fin[(size_t)dir * Bb * Hh + (size_t)b * Hh + j] = hnew;
        }
        __syncthreads();
    }
}

// GRU layer 1: input y0 [B][3][256]
__global__ __launch_bounds__(384) void gru_layer1(const float* __restrict__ y0,
                                                  const float* __restrict__ WihT,
                                                  const float* __restrict__ WhhT,
                                                  const float* __restrict__ bih,
                                                  const float* __restrict__ bhh,
                                                  float* __restrict__ fin) {
    const int b = blockIdx.x >> 1, dir = blockIdx.x & 1;
    const int j = threadIdx.x;
    __shared__ float xs[3][256];
    __shared__ float hs[128];
    __shared__ float gil[384], ghl[384];
    if (j < 256) {
#pragma unroll
        for (int t = 0; t < 3; t++)
            xs[t][j] = y0[(size_t)b * 768 + t * 256 + j];
    }
    if (j < 128) hs[j] = 0.f;
    __syncthreads();
    const float* Wi = WihT + (size_t)dir * 256 * 384;
    const float* Wh = WhhT + (size_t)dir * 128 * 384;
    float gi[3];
    gi[0] = gi[1] = gi[2] = bih[dir * 384 + j];
    for (int k = 0; k < 256; k++) {
        float w = Wi[(size_t)k * 384 + j];
        gi[0] += w * xs[0][k]; gi[1] += w * xs[1][k]; gi[2] += w * xs[2][k];
    }
    const float bhj = bhh[dir * 384 + j];
    for (int step = 0; step < 3; step++) {
        int t = dir ? 2 - step : step;
        float g = bhj;
        for (int k = 0; k < 128; k++) g += Wh[(size_t)k * 384 + j] * hs[k];
        ghl[j] = g;
        gil[j] = gi[t];
        __syncthreads();
        if (j < 128) {
            float r = sigmoidf(gil[j] + ghl[j]);
            float z = sigmoidf(gil[j + 128] + ghl[j + 128]);
            float nn2 = tanhf(gil[j + 256] + r * ghl[j + 256]);
            float hnew = (1.f - z) * nn2 + z * hs[j];
            hs[j] = hnew;
            if (step == 2) fin[(size_t)(2 + dir) * Bb * Hh + (size_t)b * Hh + j] = hnew;
        }
        __syncthreads();
    }
}

__global__ void final_mean(const float* __restrict__ fin, float* __restrict__ out) {
    int b = blockIdx.x, tid = threadIdx.x;
    const size_t s = (size_t)Bb * Hh;
    out[(size_t)b * Hh + tid] = 0.25f * (fin[b * Hh + tid] + fin[s + b * Hh + tid] +
                                         fin[2 * s + b * Hh + tid] + fin[3 * s + b * Hh + tid]);
}

// ---------------------------------------------------------------------------
extern "C" void kernel_launch(void* const* d_in, const int* in_sizes, int n_in,
                              void* d_out, int out_size, void* d_ws, size_t ws_size,
                              hipStream_t stream) {
    const float* h      = (const float*)d_in[0];
    const int*   wid    = (const int*)d_in[1];
    const int*   src    = (const int*)d_in[2];
    const int*   dst    = (const int*)d_in[3];
    const int*   gid    = (const int*)d_in[4];
    const float* projW  = (const float*)d_in[5];
    const float* projB  = (const float*)d_in[6];
    const float* convWn = (const float*)d_in[7];
    const float* convBn = (const float*)d_in[8];
    const float* convAtt= (const float*)d_in[9];
    const float* convWs = (const float*)d_in[10];
    const float* convB  = (const float*)d_in[11];
    const float* convG  = (const float*)d_in[12];
    const float* convBe = (const float*)d_in[13];
    const float* Wih0   = (const float*)d_in[14];
    const float* Whh0   = (const float*)d_in[15];
    const float* bih0   = (const float*)d_in[16];
    const float* bhh0   = (const float*)d_in[17];
    const float* Wih1   = (const float*)d_in[18];
    const float* Whh1   = (const float*)d_in[19];
    const float* bih1   = (const float*)d_in[20];
    const float* bhh1   = (const float*)d_in[21];
    float* out = (float*)d_out;

    char* p = (char*)d_ws;
    auto alloc_f = [&](size_t n) { float* r = (float*)p; p += n * sizeof(float); return r; };
    auto alloc_i = [&](size_t n) { int* r = (int*)p; p += n * sizeof(int); return r; };
    auto alloc_s = [&](size_t n) { unsigned short* r = (unsigned short*)p; p += n * sizeof(unsigned short); return r; };
    float* hcur  = alloc_f((size_t)Nn * Hh);
    float* agg   = alloc_f((size_t)Nn * 384);
    float* res   = alloc_f((size_t)Nn * Hh);
    float* adbuf = alloc_f((size_t)Nn * 4);
    float* addbuf= alloc_f((size_t)Nn * 4);
    // contiguous zero-init region: reado | deg | gcnt
    float* reado = alloc_f((size_t)3 * Bb * Hh);
    int* deg  = alloc_i(Nn);
    int* gcnt = alloc_i(Bb);
    const size_t zero_bytes = (size_t)3 * Bb * Hh * sizeof(float) + Nn * sizeof(int) + Bb * sizeof(int);
    float* y0    = alloc_f((size_t)Bb * 3 * 256);
    float* fin   = alloc_f((size_t)4 * Bb * Hh);
    float* WihT0 = alloc_f((size_t)2 * 128 * 384);
    float* WhhT0 = alloc_f((size_t)2 * 128 * 384);
    float* WihT1 = alloc_f((size_t)2 * 256 * 384);
    float* WhhT1 = alloc_f((size_t)2 * 128 * 384);
    int* offs = alloc_i(Nn + 1);
    int* cur  = alloc_i(Nn);
    int* csrc = alloc_i(Ee);
    unsigned short* wv = alloc_s((size_t)Nn * 384);   // bf16 wv
    unsigned short* pBth  = alloc_s(128 * 128);
    unsigned short* pBtl  = alloc_s(128 * 128);
    unsigned short* WnTh[2] = { alloc_s(384 * 128), alloc_s(384 * 128) };
    unsigned short* WnTl[2] = { alloc_s(384 * 128), alloc_s(384 * 128) };
    unsigned short* WsTh[2] = { alloc_s(128 * 384), alloc_s(128 * 384) };
    unsigned short* WsTl[2] = { alloc_s(128 * 384), alloc_s(128 * 384) };

    hipMemsetAsync(reado, 0, zero_bytes, stream);

    hist_dst<<<1250, 256, 0, stream>>>(dst, deg);
    scan_offsets<<<1, 1024, 0, stream>>>(deg, offs, cur);
    fill_csr<<<1250, 256, 0, stream>>>(dst, src, cur, csrc);

    PrepArgs pa;
    pa.projW = projW + (size_t)Vv * Hh; pa.convWn = convWn; pa.convWs = convWs;
    pa.Wih0 = Wih0; pa.Whh0 = Whh0; pa.Wih1 = Wih1; pa.Whh1 = Whh1;
    pa.pBth = pBth; pa.pBtl = pBtl;
    pa.WnTh0 = WnTh[0]; pa.WnTl0 = WnTl[0]; pa.WnTh1 = WnTh[1]; pa.WnTl1 = WnTl[1];
    pa.WsTh0 = WsTh[0]; pa.WsTl0 = WsTl[0]; pa.WsTh1 = WsTh[1]; pa.WsTl1 = WsTl[1];
    pa.WihT0 = WihT0; pa.WhhT0 = WhhT0; pa.WihT1 = WihT1; pa.WhhT1 = WhhT1;
    prep_all<<<(704512 + 255) / 256, 256, 0, stream>>>(pa);

    gemm_mfma_t<false><<<dim3(1, (Nn + 127) / 128), 256, 0, stream>>>(
        h, pBth, pBtl, nullptr, res, nullptr, Nn, 128, 128);
    proj_epilogue<<<Nn, 128, 0, stream>>>(res, projW, projB, wid, gid, hcur, reado, gcnt);

    const int nwaveblocks = (Nn * 64 + 255) / 256;   // 5000
    for (int l = 0; l < 2; l++) {
        gemm_mfma_t<true><<<dim3(3, (Nn + 127) / 128), 256, 0, stream>>>(
            hcur, WnTh[l], WnTl[l], convBn + l * 384, nullptr, wv, Nn, 384, 128);
        att_dots<<<nwaveblocks, 256, 0, stream>>>(wv, convAtt + (size_t)l * 3 * 256,
                                                  (float4*)adbuf, (float4*)addbuf);
        gat_aggregate<<<nwaveblocks, 256, 0, stream>>>(wv, (const float4*)adbuf, (const float4*)addbuf,
                                                       offs, csrc, agg);
        gemm_mfma_t<false><<<dim3(1, (Nn + 127) / 128), 256, 0, stream>>>(
            agg, WsTh[l], WsTl[l], convB + l * Hh, res, nullptr, Nn, 128, 384);
        ln_epilogue<<<Nn, 128, 0, stream>>>(res, deg, convG + l * Hh, convBe + l * Hh,
                                            gid, hcur, reado + (size_t)(l + 1) * Bb * Hh);
    }

    gru_layer0<<<2 * Bb, 384, 0, stream>>>(reado, gcnt, WihT0, WhhT0, bih0, bhh0, y0, fin);
    gru_layer1<<<2 * Bb, 384, 0, stream>>>(y0, WihT1, WhhT1, bih1, bhh1, fin);
    final_mean<<<Bb, 128, 0, stream>>>(fin, out);
}